// Round 2
// baseline (1777.982 us; speedup 1.0000x reference)
//
#include <hip/hip_runtime.h>
#include <math.h>

// Problem constants (b=8, n=4096, c=768, h=8, d=96)
#define NB  8
#define SEQ 4096
#define CH  768
#define NH  8
#define HD  96
#define NC3 2304   // 3*CH

// ---------------------------------------------------------------------------
// Workspace layout (floats). Total = 19,476,480 floats = 77.9 MB.
//   G  : 8 x 768 x 768          (x^T x per batch)         [reused later for P]
//   U  : 2 x 64 x 768 x 96      (G @ Wq | G @ Wk per bh)
//   INV: 2 x 64 x 96            (1/max(norm,eps))
//   AT : 64 x 96 x 96           (softmaxed attention)
//   M  : 8 x 768 x 768          (stacked A_h^T @ Wp_h)
//   P  : alias of G             (Wv @ M per batch)
// ---------------------------------------------------------------------------
static const size_t G_OFF   = 0;
static const size_t U_OFF   = G_OFF + (size_t)NB * CH * CH;            // 4,718,592
static const size_t INV_OFF = U_OFF + (size_t)2 * 64 * CH * HD;        // +9,437,184
static const size_t AT_OFF  = INV_OFF + (size_t)2 * 64 * HD;           // +12,288
static const size_t M_OFF   = AT_OFF + (size_t)64 * HD * HD;           // +589,824
static const size_t P_OFF   = G_OFF;                                    // alias (G dead)

// ---------------------------------------------------------------------------
// K_G: G[b][i][j] = sum_n x[b][n][i] * x[b][n][j]   (batched syrk, full matrix)
// grid (12, 12, 8), block 256. 64x64 tile, BK=16 over n, 4x4/thread.
// ---------------------------------------------------------------------------
__global__ void syrk_kernel(const float* __restrict__ X, float* __restrict__ G) {
  const int b  = blockIdx.z;
  const int i0 = blockIdx.y * 64, j0 = blockIdx.x * 64;
  const int tx = threadIdx.x % 16, ty = threadIdx.x / 16;
  __shared__ __align__(16) float Xi[16][64];
  __shared__ __align__(16) float Xj[16][64];
  const float* xb = X + (size_t)b * SEQ * CH;
  float acc[4][4] = {};

  for (int n0 = 0; n0 < SEQ; n0 += 16) {
    {
      int c = threadIdx.x % 64, k4 = threadIdx.x / 64;
#pragma unroll
      for (int p = 0; p < 4; ++p) {
        int k = k4 + p * 4;
        Xi[k][c] = xb[(size_t)(n0 + k) * CH + i0 + c];
        Xj[k][c] = xb[(size_t)(n0 + k) * CH + j0 + c];
      }
    }
    __syncthreads();
#pragma unroll
    for (int kk = 0; kk < 16; ++kk) {
      float4 av = *(const float4*)&Xi[kk][ty * 4];
      float4 bv = *(const float4*)&Xj[kk][tx * 4];
      float a[4] = {av.x, av.y, av.z, av.w};
      float bb[4] = {bv.x, bv.y, bv.z, bv.w};
#pragma unroll
      for (int i = 0; i < 4; ++i)
#pragma unroll
        for (int j = 0; j < 4; ++j)
          acc[i][j] += a[i] * bb[j];
    }
    __syncthreads();
  }

  float* Gb = G + (size_t)b * CH * CH;
#pragma unroll
  for (int i = 0; i < 4; ++i)
#pragma unroll
    for (int j = 0; j < 4; ++j)
      Gb[(size_t)(i0 + ty * 4 + i) * CH + j0 + tx * 4 + j] = acc[i][j];
}

// ---------------------------------------------------------------------------
// K_U: U[t][bh][i][d] = sum_j G[b][i][j] * Wqkv[j][t*768 + h*96 + d]
// grid (12 i-tiles, 64 bh, 2 t), block 256. 64x96 tile, 4x6/thread, BK=16.
// ---------------------------------------------------------------------------
__global__ void u_kernel(const float* __restrict__ G,
                         const float* __restrict__ Wqkv,
                         float* __restrict__ U) {
  const int i0 = blockIdx.x * 64;
  const int bh = blockIdx.y;
  const int t  = blockIdx.z;
  const int b = bh >> 3, h = bh & 7;
  const int cb = t * CH + h * HD;
  const int tx = threadIdx.x % 16, ty = threadIdx.x / 16;
  __shared__ __align__(16) float Gs[16][68];   // [kk][ii], pad 68: 2-way-free writes
  __shared__ float Ws[16][96];
  const float* Gb = G + (size_t)b * CH * CH;
  float acc[4][6] = {};

  for (int k0 = 0; k0 < CH; k0 += 16) {
    {
      int kk = threadIdx.x % 16, ii = threadIdx.x / 16;
#pragma unroll
      for (int p = 0; p < 4; ++p)
        Gs[kk][ii + p * 16] = Gb[(size_t)(i0 + ii + p * 16) * CH + k0 + kk];
    }
    for (int idx = threadIdx.x; idx < 16 * 96; idx += 256) {
      int jj = idx / 96, dd = idx % 96;
      Ws[jj][dd] = Wqkv[(size_t)(k0 + jj) * NC3 + cb + dd];
    }
    __syncthreads();
#pragma unroll
    for (int kk = 0; kk < 16; ++kk) {
      float4 av = *(const float4*)&Gs[kk][ty * 4];
      float a[4] = {av.x, av.y, av.z, av.w};
      float bb[6];
#pragma unroll
      for (int j = 0; j < 6; ++j) bb[j] = Ws[kk][tx * 6 + j];
#pragma unroll
      for (int i = 0; i < 4; ++i)
#pragma unroll
        for (int j = 0; j < 6; ++j)
          acc[i][j] += a[i] * bb[j];
    }
    __syncthreads();
  }

  float* Ub = U + ((size_t)t * 64 + bh) * (size_t)CH * HD;
#pragma unroll
  for (int i = 0; i < 4; ++i)
#pragma unroll
    for (int j = 0; j < 6; ++j)
      Ub[(size_t)(i0 + ty * 4 + i) * HD + tx * 6 + j] = acc[i][j];
}

// ---------------------------------------------------------------------------
// K_norm: INV[t][bh][d] = 1 / max(sqrt(sum_i U[t][bh][i][d] * W[i][cb+d]), eps)
// grid 128 (t*64+bh), block (96,4).
// ---------------------------------------------------------------------------
__global__ void norm_kernel(const float* __restrict__ U,
                            const float* __restrict__ Wqkv,
                            float* __restrict__ INVv) {
  const int t  = blockIdx.x >> 6;
  const int bh = blockIdx.x & 63;
  const int h = bh & 7;
  const int cb = t * CH + h * HD;
  const int d = threadIdx.x;     // 0..95
  const int r = threadIdx.y;     // 0..3
  const float* Ub = U + ((size_t)t * 64 + bh) * (size_t)CH * HD;

  float s = 0.f;
  for (int i = r; i < CH; i += 4)
    s += Ub[(size_t)i * HD + d] * Wqkv[(size_t)i * NC3 + cb + d];

  __shared__ float red[4][96];
  red[r][d] = s;
  __syncthreads();
  if (r == 0) {
    float tot = red[0][d] + red[1][d] + red[2][d] + red[3][d];
    tot = fmaxf(tot, 0.f);   // quadratic form: clamp rounding negatives
    INVv[(size_t)t * 64 * HD + (size_t)bh * HD + d] =
        1.0f / fmaxf(sqrtf(tot), 1e-12f);
  }
}

// ---------------------------------------------------------------------------
// K_S: S[d][e] = sum_i UQ[bh][i][d] * Wk[i][e]; scale by invq*invk*temp;
//      softmax over e; write AT[bh][d][e].  grid 64, block 256, 6x6/thread.
// ---------------------------------------------------------------------------
__global__ void s_softmax_kernel(const float* __restrict__ U,
                                 const float* __restrict__ Wqkv,
                                 const float* __restrict__ INVv,
                                 const float* __restrict__ temp,
                                 float* __restrict__ AT) {
  const int bh = blockIdx.x;
  const int h = bh & 7;
  const int tx = threadIdx.x % 16, ty = threadIdx.x / 16;
  __shared__ float UQs[16][96];
  __shared__ float Wks[16][96];
  __shared__ float S[96][97];
  const float* UQb = U + (size_t)bh * (size_t)CH * HD;   // t=0 (q) part
  float acc[6][6] = {};

  for (int k0 = 0; k0 < CH; k0 += 16) {
    for (int idx = threadIdx.x; idx < 1536; idx += 256) {
      int jj = idx / 96, dd = idx % 96;
      UQs[jj][dd] = UQb[(size_t)(k0 + jj) * HD + dd];
      Wks[jj][dd] = Wqkv[(size_t)(k0 + jj) * NC3 + CH + h * HD + dd];
    }
    __syncthreads();
#pragma unroll
    for (int kk = 0; kk < 16; ++kk) {
      float a[6], bb[6];
#pragma unroll
      for (int j = 0; j < 6; ++j) { a[j] = UQs[kk][ty * 6 + j]; bb[j] = Wks[kk][tx * 6 + j]; }
#pragma unroll
      for (int i = 0; i < 6; ++i)
#pragma unroll
        for (int j = 0; j < 6; ++j)
          acc[i][j] += a[i] * bb[j];
    }
    __syncthreads();
  }

  const float* iq = INVv + (size_t)bh * HD;
  const float* ik = INVv + (size_t)64 * HD + (size_t)bh * HD;
  const float tv = temp[h];
#pragma unroll
  for (int i = 0; i < 6; ++i)
#pragma unroll
    for (int j = 0; j < 6; ++j)
      S[ty * 6 + i][tx * 6 + j] = acc[i][j] * iq[ty * 6 + i] * ik[tx * 6 + j] * tv;
  __syncthreads();

  if (threadIdx.x < 96) {
    const int d = threadIdx.x;
    float mx = -INFINITY;
    for (int e = 0; e < 96; ++e) mx = fmaxf(mx, S[d][e]);
    float sum = 0.f;
    for (int e = 0; e < 96; ++e) {
      float ex = expf(S[d][e] - mx);
      S[d][e] = ex;
      sum += ex;
    }
    float inv = 1.0f / sum;
    float* arow = AT + (size_t)bh * HD * HD + (size_t)d * HD;
    for (int e = 0; e < 96; ++e) arow[e] = S[d][e] * inv;
  }
}

// ---------------------------------------------------------------------------
// K_M: M[b][h*96+e][j] = sum_d AT[bh][d][e] * Wp[h*96+d][j]
// grid (6 j-tiles, 64 bh), block 256. 96x128 tile, 6x8/thread, BK=16.
// ---------------------------------------------------------------------------
__global__ void m_kernel(const float* __restrict__ AT,
                         const float* __restrict__ Wp,
                         float* __restrict__ Mw) {
  const int j0 = blockIdx.x * 128;
  const int bh = blockIdx.y;
  const int b = bh >> 3, h = bh & 7;
  const int tx = threadIdx.x % 16, ty = threadIdx.x / 16;
  __shared__ float As[16][96];                  // [d-kk][e]
  __shared__ __align__(16) float Ws[16][128];   // [d-kk][j]
  const float* Ab = AT + (size_t)bh * HD * HD;
  float acc[6][8] = {};

  for (int d0 = 0; d0 < HD; d0 += 16) {
    for (int idx = threadIdx.x; idx < 1536; idx += 256) {
      int kk = idx / 96, ee = idx % 96;
      As[kk][ee] = Ab[(size_t)(d0 + kk) * HD + ee];
    }
    for (int idx = threadIdx.x; idx < 2048; idx += 256) {
      int kk = idx / 128, jj = idx % 128;
      Ws[kk][jj] = Wp[(size_t)(h * HD + d0 + kk) * CH + j0 + jj];
    }
    __syncthreads();
#pragma unroll
    for (int kk = 0; kk < 16; ++kk) {
      float a[6];
#pragma unroll
      for (int i = 0; i < 6; ++i) a[i] = As[kk][ty * 6 + i];
      float4 b0 = *(const float4*)&Ws[kk][tx * 8];
      float4 b1 = *(const float4*)&Ws[kk][tx * 8 + 4];
      float bb[8] = {b0.x, b0.y, b0.z, b0.w, b1.x, b1.y, b1.z, b1.w};
#pragma unroll
      for (int i = 0; i < 6; ++i)
#pragma unroll
        for (int j = 0; j < 8; ++j)
          acc[i][j] += a[i] * bb[j];
    }
    __syncthreads();
  }

  float* Mb = Mw + (size_t)b * CH * CH;
#pragma unroll
  for (int i = 0; i < 6; ++i)
#pragma unroll
    for (int j = 0; j < 8; ++j)
      Mb[(size_t)(h * HD + ty * 6 + i) * CH + j0 + tx * 8 + j] = acc[i][j];
}

// ---------------------------------------------------------------------------
// Generic batched NN GEMM: C[z] = A[z] (MxK) @ B[z] (KxN) (+bias), row-major.
// grid (N/64, M/64, batches), block 256. 64x64 tile, BK=16, 4x4/thread.
// Used for P = Wv @ M (strideA=0) and out = x @ P + bias.
// ---------------------------------------------------------------------------
__global__ void gemm_nn_kernel(const float* __restrict__ A,
                               const float* __restrict__ B,
                               const float* __restrict__ bias,
                               float* __restrict__ C,
                               int lda, int ldb, int ldc,
                               long sA, long sB, long sC, int K) {
  const int bz = blockIdx.z;
  const float* Ab = A + (size_t)bz * sA;
  const float* Bb = B + (size_t)bz * sB;
  float* Cb = C + (size_t)bz * sC;
  const int i0 = blockIdx.y * 64, j0 = blockIdx.x * 64;
  const int tx = threadIdx.x % 16, ty = threadIdx.x / 16;
  __shared__ __align__(16) float As[16][68];   // [kk][ii]
  __shared__ __align__(16) float Bs[16][64];   // [kk][jj]
  float acc[4][4] = {};

  for (int k0 = 0; k0 < K; k0 += 16) {
    {
      int kk = threadIdx.x % 16, ii = threadIdx.x / 16;
#pragma unroll
      for (int p = 0; p < 4; ++p)
        As[kk][ii + p * 16] = Ab[(size_t)(i0 + ii + p * 16) * lda + k0 + kk];
    }
    {
      int jj = threadIdx.x % 64, k4 = threadIdx.x / 64;
#pragma unroll
      for (int p = 0; p < 4; ++p)
        Bs[k4 + p * 4][jj] = Bb[(size_t)(k0 + k4 + p * 4) * ldb + j0 + jj];
    }
    __syncthreads();
#pragma unroll
    for (int kk = 0; kk < 16; ++kk) {
      float4 av = *(const float4*)&As[kk][ty * 4];
      float4 bv = *(const float4*)&Bs[kk][tx * 4];
      float a[4] = {av.x, av.y, av.z, av.w};
      float bb[4] = {bv.x, bv.y, bv.z, bv.w};
#pragma unroll
      for (int i = 0; i < 4; ++i)
#pragma unroll
        for (int j = 0; j < 4; ++j)
          acc[i][j] += a[i] * bb[j];
    }
    __syncthreads();
  }

#pragma unroll
  for (int i = 0; i < 4; ++i) {
#pragma unroll
    for (int j = 0; j < 4; ++j) {
      float v = acc[i][j];
      if (bias) v += bias[j0 + tx * 4 + j];
      Cb[(size_t)(i0 + ty * 4 + i) * ldc + j0 + tx * 4 + j] = v;
    }
  }
}

// ---------------------------------------------------------------------------
extern "C" void kernel_launch(void* const* d_in, const int* in_sizes, int n_in,
                              void* d_out, int out_size, void* d_ws, size_t ws_size,
                              hipStream_t stream) {
  const float* x      = (const float*)d_in[0];
  const float* W_qkv  = (const float*)d_in[1];
  const float* W_proj = (const float*)d_in[2];
  const float* b_proj = (const float*)d_in[3];
  const float* temp   = (const float*)d_in[4];
  float* out = (float*)d_out;
  float* ws  = (float*)d_ws;

  float* G   = ws + G_OFF;
  float* U   = ws + U_OFF;
  float* INV = ws + INV_OFF;
  float* AT  = ws + AT_OFF;
  float* M   = ws + M_OFF;
  float* P   = ws + P_OFF;   // aliases G (G dead by then)

  // 1. G_b = x_b^T x_b
  syrk_kernel<<<dim3(12, 12, NB), 256, 0, stream>>>(x, G);

  // 2. U[t][bh] = G_b @ W_{q|k}ated head slice
  u_kernel<<<dim3(12, 64, 2), 256, 0, stream>>>(G, W_qkv, U);

  // 3. inverse norms from diag(W^T G W)
  norm_kernel<<<128, dim3(96, 4), 0, stream>>>(U, W_qkv, INV);

  // 4. S = UQ^T Wk, scale, softmax -> AT
  s_softmax_kernel<<<64, 256, 0, stream>>>(U, W_qkv, INV, temp, AT);

  // 5. M_b[h*96+e][j] = sum_d AT[bh][d][e] Wp[h*96+d][j]
  m_kernel<<<dim3(6, 64), 256, 0, stream>>>(AT, W_proj, M);

  // 6. P_b = Wv @ M_b   (Wv = W_qkv columns 1536..2303, shared across b)
  gemm_nn_kernel<<<dim3(12, 12, NB), 256, 0, stream>>>(
      W_qkv + 2 * CH, M, nullptr, P, NC3, CH, CH, 0, (long)CH * CH, (long)CH * CH, CH);

  // 7. out_b = x_b @ P_b + b_proj
  gemm_nn_kernel<<<dim3(12, 64, NB), 256, 0, stream>>>(
      x, P, b_proj, out, CH, CH, CH, (long)SEQ * CH, (long)CH * CH, (long)SEQ * CH, CH);
}

// Round 3
// 505.293 us; speedup vs baseline: 3.5187x; 3.5187x over previous
//
#include <hip/hip_runtime.h>
#include <math.h>

// Problem constants (b=8, n=4096, c=768, h=8, d=96)
#define NB  8
#define SEQ 4096
#define CH  768
#define NH  8
#define HD  96
#define NC3 2304   // 3*CH

typedef _Float16 f16x8 __attribute__((ext_vector_type(8)));
typedef float    f32x4 __attribute__((ext_vector_type(4)));

// ---------------------------------------------------------------------------
// Workspace layout (BYTE offsets). Total 68,075,520 B = 68.1 MB.
// Region [XT .. XT+50.3MB) first holds xt (fp16 [b][c][n]); xt dies after
// syrk, then the same region holds Ut, Spart, ATt, Mt, Pt (48.4MB).
// ---------------------------------------------------------------------------
static const size_t XT_B    = 0;                       // 25,165,824 halves
static const size_t UT_B    = 0;                       // 2*8*768*768 halves = 18,874,368 B
static const size_t SPART_B = 18874368;                // 4*64*9216 floats   =  9,437,184 B
static const size_t ATT_B   = 28311552;                // 64*9216 halves     =  1,179,648 B
static const size_t MT_B    = 29491200;                // 8*768*768 halves   =  9,437,184 B
static const size_t PT_B    = 38928384;                // 8*768*768 halves   =  9,437,184 B
static const size_t G_B     = 50331648;                // 8*768*768 halves   =  9,437,184 B
static const size_t WH_B    = 59768832;                // 768*2304 halves    =  3,538,944 B
static const size_t WT_B    = 63307776;                // 2304*768 halves    =  3,538,944 B
static const size_t WPT_B   = 66846720;                // 768*768 halves     =  1,179,648 B
static const size_t INV_B   = 68026368;                // 16*768 floats      =     49,152 B

// ---------------------------------------------------------------------------
// Elementwise fp32 -> fp16 convert (vectorized by 4)
// ---------------------------------------------------------------------------
__global__ void cvt_f16_kernel(const float* __restrict__ in,
                               _Float16* __restrict__ out, int n4) {
  int i = blockIdx.x * blockDim.x + threadIdx.x;
  if (i < n4) {
    float4 v = *(const float4*)(in + (size_t)i * 4);
    _Float16* o = out + (size_t)i * 4;
    o[0] = (_Float16)v.x; o[1] = (_Float16)v.y;
    o[2] = (_Float16)v.z; o[3] = (_Float16)v.w;
  }
}

// ---------------------------------------------------------------------------
// Tiled transpose + convert: in fp32 [R][C] -> out fp16 [C][R], batched.
// grid (C/32, R/32, batch), block 256 (32x8).
// ---------------------------------------------------------------------------
__global__ void transpose_cvt_kernel(const float* __restrict__ in,
                                     _Float16* __restrict__ out,
                                     int R, int C, long sIn, long sOut) {
  __shared__ float t[32][33];
  const int b = blockIdx.z;
  const int c0 = blockIdx.x * 32, r0 = blockIdx.y * 32;
  const int tx = threadIdx.x & 31, ty = threadIdx.x >> 5;   // ty 0..7
  const float* ib = in + (size_t)b * sIn;
  _Float16* ob = out + (size_t)b * sOut;
#pragma unroll
  for (int k = 0; k < 4; ++k)
    t[ty + 8 * k][tx] = ib[(size_t)(r0 + ty + 8 * k) * C + c0 + tx];
  __syncthreads();
#pragma unroll
  for (int k = 0; k < 4; ++k)
    ob[(size_t)(c0 + ty + 8 * k) * R + r0 + tx] = (_Float16)t[tx][ty + 8 * k];
}

// ---------------------------------------------------------------------------
// MFMA GEMM:  C[M][N] = A[M][K] * B[N][K]^T  (+ bias over N)
// A fp16 (or fp32 converted on the fly), B fp16, C fp32 or fp16.
// 128x128 tile, BK=32, 256 threads = 4 waves, each wave a 64x64 quadrant
// (4x4 fragments of 16x16x32). LDS rows 64B, XOR slot swizzle (row>>1)&3
// -> conflict-free-ish ds_read_b128 fragment loads.
// Requires: M%128==0, N%128==0, K%32==0.
// ---------------------------------------------------------------------------
template<bool A_FP32, bool FP16OUT, bool BIAS>
__global__ __launch_bounds__(256) void gemm_bt_mfma(
    const void* __restrict__ Ap, const _Float16* __restrict__ Bp,
    const float* __restrict__ bias, void* __restrict__ Cp,
    int K, int lda, int ldb, int ldc, long sA, long sB, long sC) {
  __shared__ __align__(16) _Float16 ldsA[128 * 32];
  __shared__ __align__(16) _Float16 ldsB[128 * 32];

  const int bz = blockIdx.z;
  const int row0 = blockIdx.y * 128, col0 = blockIdx.x * 128;
  const int tid = threadIdx.x;
  const int l = tid & 63, w = tid >> 6;
  const int lo = l & 15, hi = l >> 4;
  const int wr = w >> 1, wc = w & 1;

  const float*    Af32 = (const float*)Ap + (size_t)bz * sA;
  const _Float16* Af16 = (const _Float16*)Ap + (size_t)bz * sA;
  const _Float16* B    = Bp + (size_t)bz * sB;

  // staging assignment: thread covers row R, 16 halves at k-offset cs
  const int R  = tid >> 1;
  const int cs = (tid & 1) * 16;
  const int slot0 = (tid & 1) * 2;
  const int m_sw  = (R >> 1) & 3;

  f32x4 acc[4][4];
#pragma unroll
  for (int i = 0; i < 4; ++i)
#pragma unroll
    for (int j = 0; j < 4; ++j)
      acc[i][j] = (f32x4){0.f, 0.f, 0.f, 0.f};

  for (int k0 = 0; k0 < K; k0 += 32) {
    // ---- stage A tile ----
    f16x8 h0, h1;
    if constexpr (A_FP32) {
      const float* src = Af32 + (size_t)(row0 + R) * lda + k0 + cs;
      float4 v0 = *(const float4*)(src);
      float4 v1 = *(const float4*)(src + 4);
      float4 v2 = *(const float4*)(src + 8);
      float4 v3 = *(const float4*)(src + 12);
      h0 = (f16x8){(_Float16)v0.x, (_Float16)v0.y, (_Float16)v0.z, (_Float16)v0.w,
                   (_Float16)v1.x, (_Float16)v1.y, (_Float16)v1.z, (_Float16)v1.w};
      h1 = (f16x8){(_Float16)v2.x, (_Float16)v2.y, (_Float16)v2.z, (_Float16)v2.w,
                   (_Float16)v3.x, (_Float16)v3.y, (_Float16)v3.z, (_Float16)v3.w};
    } else {
      const _Float16* src = Af16 + (size_t)(row0 + R) * lda + k0 + cs;
      h0 = *(const f16x8*)(src);
      h1 = *(const f16x8*)(src + 8);
    }
    *(f16x8*)&ldsA[R * 32 + ((slot0)     ^ m_sw) * 8] = h0;
    *(f16x8*)&ldsA[R * 32 + ((slot0 | 1) ^ m_sw) * 8] = h1;
    // ---- stage B tile ----
    {
      const _Float16* src = B + (size_t)(col0 + R) * ldb + k0 + cs;
      f16x8 g0 = *(const f16x8*)(src);
      f16x8 g1 = *(const f16x8*)(src + 8);
      *(f16x8*)&ldsB[R * 32 + ((slot0)     ^ m_sw) * 8] = g0;
      *(f16x8*)&ldsB[R * 32 + ((slot0 | 1) ^ m_sw) * 8] = g1;
    }
    __syncthreads();

    f16x8 a[4], b[4];
#pragma unroll
    for (int mi = 0; mi < 4; ++mi) {
      int Ra = 64 * wr + 16 * mi + lo;
      a[mi] = *(const f16x8*)&ldsA[Ra * 32 + (hi ^ ((Ra >> 1) & 3)) * 8];
    }
#pragma unroll
    for (int ni = 0; ni < 4; ++ni) {
      int Rb = 64 * wc + 16 * ni + lo;
      b[ni] = *(const f16x8*)&ldsB[Rb * 32 + (hi ^ ((Rb >> 1) & 3)) * 8];
    }
#pragma unroll
    for (int mi = 0; mi < 4; ++mi)
#pragma unroll
      for (int ni = 0; ni < 4; ++ni)
        acc[mi][ni] = __builtin_amdgcn_mfma_f32_16x16x32_f16(
            a[mi], b[ni], acc[mi][ni], 0, 0, 0);
    __syncthreads();
  }

  // ---- epilogue: D[row][col], col = lane&15, row = 4*(lane>>4)+reg ----
#pragma unroll
  for (int ni = 0; ni < 4; ++ni) {
    const int col = col0 + 64 * wc + 16 * ni + lo;
    float bv = 0.f;
    if constexpr (BIAS) bv = bias[col];
#pragma unroll
    for (int mi = 0; mi < 4; ++mi) {
      const int rowb = row0 + 64 * wr + 16 * mi + 4 * hi;
#pragma unroll
      for (int r = 0; r < 4; ++r) {
        float v = acc[mi][ni][r] + bv;
        if constexpr (FP16OUT)
          ((_Float16*)Cp)[(size_t)bz * sC + (size_t)(rowb + r) * ldc + col] = (_Float16)v;
        else
          ((float*)Cp)[(size_t)bz * sC + (size_t)(rowb + r) * ldc + col] = v;
      }
    }
  }
}

// ---------------------------------------------------------------------------
// Norms: INV[t][b][c] = 1/max(sqrt(sum_i Ut[t][b][c][i]*Wt[t*768+c][i]),eps)
// grid 16 (t*8+b), block 256.
// ---------------------------------------------------------------------------
__global__ void norm_kernel(const _Float16* __restrict__ Ut,
                            const _Float16* __restrict__ Wt,
                            float* __restrict__ INVv) {
  const int z = blockIdx.x;           // t*8+b
  const int t = z >> 3;
  for (int c = threadIdx.x; c < CH; c += 256) {
    const _Float16* u = Ut + ((size_t)z * CH + c) * CH;
    const _Float16* wv = Wt + ((size_t)(t * CH + c)) * CH;
    float s = 0.f;
    for (int i = 0; i < CH; i += 8) {
      f16x8 uv = *(const f16x8*)(u + i);
      f16x8 wq = *(const f16x8*)(wv + i);
#pragma unroll
      for (int q = 0; q < 8; ++q) s += (float)uv[q] * (float)wq[q];
    }
    s = fmaxf(s, 0.f);
    INVv[(size_t)z * CH + c] = 1.0f / fmaxf(sqrtf(s), 1e-12f);
  }
}

// ---------------------------------------------------------------------------
// S partial: Spart[chunk][bh][d][e] = sum_{i in chunk(192)} Wt[h96+d][i]*Ut1[b][h96+e][i]
// grid (4, 64), block 256 (16x16, 6x6/thread).
// ---------------------------------------------------------------------------
__global__ void spart_kernel(const _Float16* __restrict__ Wt,
                             const _Float16* __restrict__ Ut,
                             float* __restrict__ Spart) {
  const int chunk = blockIdx.x, bh = blockIdx.y;
  const int b = bh >> 3, h = bh & 7;
  const int tx = threadIdx.x & 15, ty = threadIdx.x >> 4;
  __shared__ float As[16][96], Bs[16][96];
  const int i0 = chunk * 192;
  float acc[6][6] = {};

  for (int kk0 = 0; kk0 < 192; kk0 += 16) {
    if (threadIdx.x < 192) {
      int row = threadIdx.x >> 1, s8 = (threadIdx.x & 1) * 8;
      f16x8 av = *(const f16x8*)(Wt + (size_t)(h * HD + row) * CH + i0 + kk0 + s8);
      f16x8 bv = *(const f16x8*)(Ut + ((size_t)(8 + b) * CH + h * HD + row) * CH + i0 + kk0 + s8);
#pragma unroll
      for (int q = 0; q < 8; ++q) {
        As[s8 + q][row] = (float)av[q];
        Bs[s8 + q][row] = (float)bv[q];
      }
    }
    __syncthreads();
#pragma unroll
    for (int kk = 0; kk < 16; ++kk) {
      float a[6], bb[6];
#pragma unroll
      for (int j = 0; j < 6; ++j) { a[j] = As[kk][ty * 6 + j]; bb[j] = Bs[kk][tx * 6 + j]; }
#pragma unroll
      for (int i = 0; i < 6; ++i)
#pragma unroll
        for (int j = 0; j < 6; ++j)
          acc[i][j] += a[i] * bb[j];
    }
    __syncthreads();
  }

  float* o = Spart + ((size_t)chunk * 64 + bh) * 9216;
#pragma unroll
  for (int i = 0; i < 6; ++i)
#pragma unroll
    for (int j = 0; j < 6; ++j)
      o[(size_t)(ty * 6 + i) * 96 + tx * 6 + j] = acc[i][j];
}

// ---------------------------------------------------------------------------
// Combine partials + scale + softmax over e + transposed fp16 write:
// ATt[bh][e][d] = softmax_e( Spart_sum * invq[d]*invk[e]*temp[h] )
// grid 64, block 256.
// ---------------------------------------------------------------------------
__global__ void softmaxT_kernel(const float* __restrict__ Spart,
                                const float* __restrict__ INVv,
                                const float* __restrict__ temp,
                                _Float16* __restrict__ ATt) {
  const int bh = blockIdx.x;
  const int b = bh >> 3, h = bh & 7;
  __shared__ float S[96][97];
  const float tv = temp[h];
  const float* iq = INVv + (size_t)b * CH + h * HD;
  const float* ik = INVv + (size_t)(8 + b) * CH + h * HD;

  for (int i = threadIdx.x; i < 9216; i += 256) {
    float s = 0.f;
#pragma unroll
    for (int c = 0; c < 4; ++c) s += Spart[((size_t)c * 64 + bh) * 9216 + i];
    int d = i / 96, e = i % 96;
    S[d][e] = s * iq[d] * ik[e] * tv;
  }
  __syncthreads();

  if (threadIdx.x < 96) {
    const int d = threadIdx.x;
    float mx = -INFINITY;
    for (int e = 0; e < 96; ++e) mx = fmaxf(mx, S[d][e]);
    float sum = 0.f;
    for (int e = 0; e < 96; ++e) {
      float ex = expf(S[d][e] - mx);
      S[d][e] = ex;
      sum += ex;
    }
    float inv = 1.0f / sum;
    _Float16* ab = ATt + (size_t)bh * 9216;
    for (int e = 0; e < 96; ++e)
      ab[(size_t)e * 96 + d] = (_Float16)(S[d][e] * inv);
  }
}

// ---------------------------------------------------------------------------
// Mt[b][j][h*96+e] = sum_d Wpt[j][h96+d] * ATt[bh][e][d]
// grid (6 j-tiles, 64 bh), block 256 (16x16, 8x6/thread). K=96.
// ---------------------------------------------------------------------------
__global__ void mt_kernel(const _Float16* __restrict__ Wpt,
                          const _Float16* __restrict__ ATt,
                          _Float16* __restrict__ Mt) {
  const int j0 = blockIdx.x * 128;
  const int bh = blockIdx.y;
  const int b = bh >> 3, h = bh & 7;
  const int tx = threadIdx.x & 15, ty = threadIdx.x >> 4;
  __shared__ float Ws[16][128], Ats[16][96];
  float acc[8][6] = {};

  for (int d0 = 0; d0 < 96; d0 += 16) {
    {
      int jj = threadIdx.x >> 1, s8 = (threadIdx.x & 1) * 8;
      f16x8 v = *(const f16x8*)(Wpt + (size_t)(j0 + jj) * CH + h * HD + d0 + s8);
#pragma unroll
      for (int q = 0; q < 8; ++q) Ws[s8 + q][jj] = (float)v[q];
    }
    if (threadIdx.x < 192) {
      int e = threadIdx.x >> 1, s8 = (threadIdx.x & 1) * 8;
      f16x8 v = *(const f16x8*)(ATt + (size_t)bh * 9216 + (size_t)e * 96 + d0 + s8);
#pragma unroll
      for (int q = 0; q < 8; ++q) Ats[s8 + q][e] = (float)v[q];
    }
    __syncthreads();
#pragma unroll
    for (int kk = 0; kk < 16; ++kk) {
      float a[8], bb[6];
#pragma unroll
      for (int i = 0; i < 8; ++i) a[i] = Ws[kk][ty * 8 + i];
#pragma unroll
      for (int j = 0; j < 6; ++j) bb[j] = Ats[kk][tx * 6 + j];
#pragma unroll
      for (int i = 0; i < 8; ++i)
#pragma unroll
        for (int j = 0; j < 6; ++j)
          acc[i][j] += a[i] * bb[j];
    }
    __syncthreads();
  }

  _Float16* mb = Mt + (size_t)b * CH * CH;
#pragma unroll
  for (int i = 0; i < 8; ++i)
#pragma unroll
    for (int j = 0; j < 6; ++j)
      mb[(size_t)(j0 + ty * 8 + i) * CH + h * HD + tx * 6 + j] = (_Float16)acc[i][j];
}

// ---------------------------------------------------------------------------
extern "C" void kernel_launch(void* const* d_in, const int* in_sizes, int n_in,
                              void* d_out, int out_size, void* d_ws, size_t ws_size,
                              hipStream_t stream) {
  const float* x      = (const float*)d_in[0];
  const float* W_qkv  = (const float*)d_in[1];
  const float* W_proj = (const float*)d_in[2];
  const float* b_proj = (const float*)d_in[3];
  const float* temp   = (const float*)d_in[4];
  float* out = (float*)d_out;
  char* ws = (char*)d_ws;

  _Float16* XT  = (_Float16*)(ws + XT_B);
  _Float16* UT  = (_Float16*)(ws + UT_B);
  float*    SP  = (float*)   (ws + SPART_B);
  _Float16* ATT = (_Float16*)(ws + ATT_B);
  _Float16* MT  = (_Float16*)(ws + MT_B);
  _Float16* PT  = (_Float16*)(ws + PT_B);
  _Float16* G   = (_Float16*)(ws + G_B);
  _Float16* WH  = (_Float16*)(ws + WH_B);
  _Float16* WT  = (_Float16*)(ws + WT_B);
  _Float16* WPT = (_Float16*)(ws + WPT_B);
  float*    INV = (float*)   (ws + INV_B);

  const long CC = (long)CH * CH;           // 589824

  // --- converts / transposes ---
  cvt_f16_kernel<<<(CH * NC3 / 4 + 255) / 256, 256, 0, stream>>>(W_qkv, WH, CH * NC3 / 4);
  transpose_cvt_kernel<<<dim3(CH / 32, SEQ / 32, NB), 256, 0, stream>>>(
      x, XT, SEQ, CH, (long)SEQ * CH, (long)SEQ * CH);
  transpose_cvt_kernel<<<dim3(NC3 / 32, CH / 32, 1), 256, 0, stream>>>(
      W_qkv, WT, CH, NC3, 0, 0);
  transpose_cvt_kernel<<<dim3(CH / 32, CH / 32, 1), 256, 0, stream>>>(
      W_proj, WPT, CH, CH, 0, 0);

  // --- G_b = xt_b . xt_b^T  (M=N=768, K=4096) ---
  gemm_bt_mfma<false, true, false><<<dim3(6, 6, NB), 256, 0, stream>>>(
      XT, XT, nullptr, G, SEQ, SEQ, SEQ, CH, (long)CH * SEQ, (long)CH * SEQ, CC);

  // --- Ut[t][b] = Wt_t . G_b^T  (M=N=768, K=768), t = 0(q), 1(k) ---
  for (int t = 0; t < 2; ++t)
    gemm_bt_mfma<false, true, false><<<dim3(6, 6, NB), 256, 0, stream>>>(
        WT + (size_t)t * CC, G, nullptr, UT + (size_t)t * NB * CC,
        CH, CH, CH, CH, 0, CC, CC);

  // --- norms ---
  norm_kernel<<<16, 256, 0, stream>>>(UT, WT, INV);

  // --- S partials + softmax(+transpose) ---
  spart_kernel<<<dim3(4, 64), 256, 0, stream>>>(WT, UT, SP);
  softmaxT_kernel<<<64, 256, 0, stream>>>(SP, INV, temp, ATT);

  // --- Mt ---
  mt_kernel<<<dim3(6, 64), 256, 0, stream>>>(WPT, ATT, MT);

  // --- Pt_b = Mt_b . Wv^T  (M=N=768, K=768; Wv rows via WH ldb=2304) ---
  gemm_bt_mfma<false, true, false><<<dim3(6, 6, NB), 256, 0, stream>>>(
      MT, WH + 2 * CH, nullptr, PT, CH, CH, NC3, CH, CC, 0, CC);

  // --- out_b = x_b . Pt_b^T + bias  (M=4096, N=768, K=768, fp32 A & C) ---
  gemm_bt_mfma<true, false, true><<<dim3(6, SEQ / 128, NB), 256, 0, stream>>>(
      x, PT, b_proj, out, CH, CH, CH, CH, (long)SEQ * CH, CC, (long)SEQ * CH);
}

// Round 4
// 414.265 us; speedup vs baseline: 4.2919x; 1.2197x over previous
//
#include <hip/hip_runtime.h>
#include <math.h>

// Problem constants (b=8, n=4096, c=768, h=8, d=96)
#define NB  8
#define SEQ 4096
#define CH  768
#define NH  8
#define HD  96
#define NC3 2304   // 3*CH

typedef _Float16 f16x8 __attribute__((ext_vector_type(8)));
typedef float    f32x4 __attribute__((ext_vector_type(4)));

// ---------------------------------------------------------------------------
// Workspace layout (BYTE offsets). Base layout = 68.1 MB (proven). XH (fp16
// row-major x, 50.3 MB) appended at the end, used only if ws_size allows.
// ---------------------------------------------------------------------------
static const size_t XT_B    = 0;                       // fp16 x^T  [b][c][n]
static const size_t UT_B    = 0;                       // overlays XT after G
static const size_t SPART_B = 18874368;
static const size_t ATT_B   = 28311552;
static const size_t MT_B    = 29491200;
static const size_t PT_B    = 38928384;
static const size_t G_B     = 50331648;
static const size_t WH_B    = 59768832;
static const size_t WT_B    = 63307776;
static const size_t WPT_B   = 66846720;
static const size_t INV_B   = 68026368;
static const size_t XH_B    = 68075520;                // fp16 x [b][n][c]
static const size_t XH_BYTES = (size_t)NB * SEQ * CH * 2;   // 50,331,648

// ---------------------------------------------------------------------------
// async global->LDS, 16 B per lane (wave-uniform LDS base + lane*16)
// ---------------------------------------------------------------------------
__device__ __forceinline__ void gload16(const void* g, void* l) {
  __builtin_amdgcn_global_load_lds(
      (const __attribute__((address_space(1))) void*)g,
      (__attribute__((address_space(3))) void*)l, 16, 0, 0);
}

// ---------------------------------------------------------------------------
// Elementwise fp32 -> fp16 convert (vectorized by 4)
// ---------------------------------------------------------------------------
__global__ void cvt_f16_kernel(const float* __restrict__ in,
                               _Float16* __restrict__ out, int n4) {
  int i = blockIdx.x * blockDim.x + threadIdx.x;
  if (i < n4) {
    float4 v = *(const float4*)(in + (size_t)i * 4);
    _Float16* o = out + (size_t)i * 4;
    o[0] = (_Float16)v.x; o[1] = (_Float16)v.y;
    o[2] = (_Float16)v.z; o[3] = (_Float16)v.w;
  }
}

// ---------------------------------------------------------------------------
// Tiled transpose+convert: fp32 [R][C] -> fp16 [C][R] (outT), and optionally
// straight fp16 [R][C] (outH). grid (C/32, R/32, batch), block 256.
// ---------------------------------------------------------------------------
__global__ void transpose_cvt_kernel(const float* __restrict__ in,
                                     _Float16* __restrict__ outT,
                                     _Float16* __restrict__ outH,
                                     int R, int C, long sIn, long sOut) {
  __shared__ float t[32][33];
  const int b = blockIdx.z;
  const int c0 = blockIdx.x * 32, r0 = blockIdx.y * 32;
  const int tx = threadIdx.x & 31, ty = threadIdx.x >> 5;   // ty 0..7
  const float* ib = in + (size_t)b * sIn;
  _Float16* ob = outT + (size_t)b * sOut;
#pragma unroll
  for (int k = 0; k < 4; ++k) {
    float v = ib[(size_t)(r0 + ty + 8 * k) * C + c0 + tx];
    t[ty + 8 * k][tx] = v;
    if (outH)
      outH[(size_t)b * sOut + (size_t)(r0 + ty + 8 * k) * C + c0 + tx] = (_Float16)v;
  }
  __syncthreads();
#pragma unroll
  for (int k = 0; k < 4; ++k)
    ob[(size_t)(c0 + ty + 8 * k) * R + r0 + tx] = (_Float16)t[tx][ty + 8 * k];
}

// ---------------------------------------------------------------------------
// MFMA GEMM:  C[M][N] = A[M][K] * B[N][K]^T  (+ bias over N)
// 128x128 tile, BK=32, 4 waves, 4x4 16x16x32 fragments per wave.
// GLL=true: global_load_lds staging with source-side XOR swizzle
//           (chunk = slot ^ ((row>>1)&3)); LDS stays linear; ds_read applies
//           the same XOR. GLL=false: reg-staged (supports fp32 A).
// Requires M%128==0, N%128==0, K%32==0.
// ---------------------------------------------------------------------------
template<bool A_FP32, bool FP16OUT, bool BIAS, bool GLL>
__global__ __launch_bounds__(256) void gemm_bt_mfma(
    const void* __restrict__ Ap, const _Float16* __restrict__ Bp,
    const float* __restrict__ bias, void* __restrict__ Cp,
    int K, int lda, int ldb, int ldc, long sA, long sB, long sC) {
  __shared__ __align__(16) _Float16 ldsA[128 * 32];
  __shared__ __align__(16) _Float16 ldsB[128 * 32];

  const int bz = blockIdx.z;
  const int row0 = blockIdx.y * 128, col0 = blockIdx.x * 128;
  const int tid = threadIdx.x;
  const int l = tid & 63, w = tid >> 6;
  const int lo = l & 15, hi = l >> 4;
  const int wr = w >> 1, wc = w & 1;

  const float*    Af32 = (const float*)Ap + (size_t)bz * sA;
  const _Float16* Af16 = (const _Float16*)Ap + (size_t)bz * sA;
  const _Float16* B    = Bp + (size_t)bz * sB;

  // reg-staged path assignment
  const int R  = tid >> 1;
  const int cs = (tid & 1) * 16;
  const int slot0 = (tid & 1) * 2;
  const int m_sw  = (R >> 1) & 3;
  // GLL path assignment: wave covers rows rw..rw+31, 2 calls of 16 rows
  const int rw = 32 * w;
  const int lr = l >> 2;        // row within 16-row group
  const int ls = l & 3;         // 16B slot within 64B row

  f32x4 acc[4][4];
#pragma unroll
  for (int i = 0; i < 4; ++i)
#pragma unroll
    for (int j = 0; j < 4; ++j)
      acc[i][j] = (f32x4){0.f, 0.f, 0.f, 0.f};

  for (int k0 = 0; k0 < K; k0 += 32) {
    if constexpr (GLL) {
#pragma unroll
      for (int q = 0; q < 2; ++q) {
        const int r = rw + 16 * q + lr;
        const int ck = ls ^ ((r >> 1) & 3);     // source-side swizzle
        gload16(Af16 + (size_t)(row0 + r) * lda + k0 + 8 * ck,
                &ldsA[(rw + 16 * q) * 32]);
        gload16(B + (size_t)(col0 + r) * ldb + k0 + 8 * ck,
                &ldsB[(rw + 16 * q) * 32]);
      }
    } else {
      f16x8 h0, h1;
      if constexpr (A_FP32) {
        const float* src = Af32 + (size_t)(row0 + R) * lda + k0 + cs;
        float4 v0 = *(const float4*)(src);
        float4 v1 = *(const float4*)(src + 4);
        float4 v2 = *(const float4*)(src + 8);
        float4 v3 = *(const float4*)(src + 12);
        h0 = (f16x8){(_Float16)v0.x, (_Float16)v0.y, (_Float16)v0.z, (_Float16)v0.w,
                     (_Float16)v1.x, (_Float16)v1.y, (_Float16)v1.z, (_Float16)v1.w};
        h1 = (f16x8){(_Float16)v2.x, (_Float16)v2.y, (_Float16)v2.z, (_Float16)v2.w,
                     (_Float16)v3.x, (_Float16)v3.y, (_Float16)v3.z, (_Float16)v3.w};
      } else {
        const _Float16* src = Af16 + (size_t)(row0 + R) * lda + k0 + cs;
        h0 = *(const f16x8*)(src);
        h1 = *(const f16x8*)(src + 8);
      }
      *(f16x8*)&ldsA[R * 32 + ((slot0)     ^ m_sw) * 8] = h0;
      *(f16x8*)&ldsA[R * 32 + ((slot0 | 1) ^ m_sw) * 8] = h1;
      {
        const _Float16* src = B + (size_t)(col0 + R) * ldb + k0 + cs;
        f16x8 g0 = *(const f16x8*)(src);
        f16x8 g1 = *(const f16x8*)(src + 8);
        *(f16x8*)&ldsB[R * 32 + ((slot0)     ^ m_sw) * 8] = g0;
        *(f16x8*)&ldsB[R * 32 + ((slot0 | 1) ^ m_sw) * 8] = g1;
      }
    }
    __syncthreads();

    f16x8 a[4], b[4];
#pragma unroll
    for (int mi = 0; mi < 4; ++mi) {
      int Ra = 64 * wr + 16 * mi + lo;
      a[mi] = *(const f16x8*)&ldsA[Ra * 32 + (hi ^ ((Ra >> 1) & 3)) * 8];
    }
#pragma unroll
    for (int ni = 0; ni < 4; ++ni) {
      int Rb = 64 * wc + 16 * ni + lo;
      b[ni] = *(const f16x8*)&ldsB[Rb * 32 + (hi ^ ((Rb >> 1) & 3)) * 8];
    }
#pragma unroll
    for (int mi = 0; mi < 4; ++mi)
#pragma unroll
      for (int ni = 0; ni < 4; ++ni)
        acc[mi][ni] = __builtin_amdgcn_mfma_f32_16x16x32_f16(
            a[mi], b[ni], acc[mi][ni], 0, 0, 0);
    __syncthreads();
  }

  // epilogue: D[row][col], col = lane&15, row = 4*(lane>>4)+reg
#pragma unroll
  for (int ni = 0; ni < 4; ++ni) {
    const int col = col0 + 64 * wc + 16 * ni + lo;
    float bv = 0.f;
    if constexpr (BIAS) bv = bias[col];
#pragma unroll
    for (int mi = 0; mi < 4; ++mi) {
      const int rowb = row0 + 64 * wr + 16 * mi + 4 * hi;
#pragma unroll
      for (int r = 0; r < 4; ++r) {
        float v = acc[mi][ni][r] + bv;
        if constexpr (FP16OUT)
          ((_Float16*)Cp)[(size_t)bz * sC + (size_t)(rowb + r) * ldc + col] = (_Float16)v;
        else
          ((float*)Cp)[(size_t)bz * sC + (size_t)(rowb + r) * ldc + col] = v;
      }
    }
  }
}

// ---------------------------------------------------------------------------
// Norms: INV[t][b][c] = 1/max(sqrt(sum_i Ut[t][b][c][i]*Wt[t*768+c][i]),eps)
// grid (16, 6), block 128.
// ---------------------------------------------------------------------------
__global__ void norm_kernel(const _Float16* __restrict__ Ut,
                            const _Float16* __restrict__ Wt,
                            float* __restrict__ INVv) {
  const int z = blockIdx.x;           // t*8+b
  const int t = z >> 3;
  const int c = blockIdx.y * 128 + threadIdx.x;
  const _Float16* u = Ut + ((size_t)z * CH + c) * CH;
  const _Float16* wv = Wt + ((size_t)(t * CH + c)) * CH;
  float s = 0.f;
  for (int i = 0; i < CH; i += 8) {
    f16x8 uv = *(const f16x8*)(u + i);
    f16x8 wq = *(const f16x8*)(wv + i);
#pragma unroll
    for (int q = 0; q < 8; ++q) s += (float)uv[q] * (float)wq[q];
  }
  s = fmaxf(s, 0.f);
  INVv[(size_t)z * CH + c] = 1.0f / fmaxf(sqrtf(s), 1e-12f);
}

// ---------------------------------------------------------------------------
// S partial: Spart[chunk][bh][d][e] = sum_{i in chunk} Wt[h96+d][i]*Ut1[b][h96+e][i]
// grid (4, 64), block 256 (16x16, 6x6/thread).
// ---------------------------------------------------------------------------
__global__ void spart_kernel(const _Float16* __restrict__ Wt,
                             const _Float16* __restrict__ Ut,
                             float* __restrict__ Spart) {
  const int chunk = blockIdx.x, bh = blockIdx.y;
  const int b = bh >> 3, h = bh & 7;
  const int tx = threadIdx.x & 15, ty = threadIdx.x >> 4;
  __shared__ float As[16][96], Bs[16][96];
  const int i0 = chunk * 192;
  float acc[6][6] = {};

  for (int kk0 = 0; kk0 < 192; kk0 += 16) {
    if (threadIdx.x < 192) {
      int row = threadIdx.x >> 1, s8 = (threadIdx.x & 1) * 8;
      f16x8 av = *(const f16x8*)(Wt + (size_t)(h * HD + row) * CH + i0 + kk0 + s8);
      f16x8 bv = *(const f16x8*)(Ut + ((size_t)(8 + b) * CH + h * HD + row) * CH + i0 + kk0 + s8);
#pragma unroll
      for (int q = 0; q < 8; ++q) {
        As[s8 + q][row] = (float)av[q];
        Bs[s8 + q][row] = (float)bv[q];
      }
    }
    __syncthreads();
#pragma unroll
    for (int kk = 0; kk < 16; ++kk) {
      float a[6], bb[6];
#pragma unroll
      for (int j = 0; j < 6; ++j) { a[j] = As[kk][ty * 6 + j]; bb[j] = Bs[kk][tx * 6 + j]; }
#pragma unroll
      for (int i = 0; i < 6; ++i)
#pragma unroll
        for (int j = 0; j < 6; ++j)
          acc[i][j] += a[i] * bb[j];
    }
    __syncthreads();
  }

  float* o = Spart + ((size_t)chunk * 64 + bh) * 9216;
#pragma unroll
  for (int i = 0; i < 6; ++i)
#pragma unroll
    for (int j = 0; j < 6; ++j)
      o[(size_t)(ty * 6 + i) * 96 + tx * 6 + j] = acc[i][j];
}

// ---------------------------------------------------------------------------
// Combine partials + scale + softmax over e + transposed fp16 write.
// grid 64, block 256.
// ---------------------------------------------------------------------------
__global__ void softmaxT_kernel(const float* __restrict__ Spart,
                                const float* __restrict__ INVv,
                                const float* __restrict__ temp,
                                _Float16* __restrict__ ATt) {
  const int bh = blockIdx.x;
  const int b = bh >> 3, h = bh & 7;
  __shared__ float S[96][97];
  const float tv = temp[h];
  const float* iq = INVv + (size_t)b * CH + h * HD;
  const float* ik = INVv + (size_t)(8 + b) * CH + h * HD;

  for (int i = threadIdx.x; i < 9216; i += 256) {
    float s = 0.f;
#pragma unroll
    for (int c = 0; c < 4; ++c) s += Spart[((size_t)c * 64 + bh) * 9216 + i];
    int d = i / 96, e = i % 96;
    S[d][e] = s * iq[d] * ik[e] * tv;
  }
  __syncthreads();

  if (threadIdx.x < 96) {
    const int d = threadIdx.x;
    float mx = -INFINITY;
    for (int e = 0; e < 96; ++e) mx = fmaxf(mx, S[d][e]);
    float sum = 0.f;
    for (int e = 0; e < 96; ++e) {
      float ex = expf(S[d][e] - mx);
      S[d][e] = ex;
      sum += ex;
    }
    float inv = 1.0f / sum;
    _Float16* ab = ATt + (size_t)bh * 9216;
    for (int e = 0; e < 96; ++e)
      ab[(size_t)e * 96 + d] = (_Float16)(S[d][e] * inv);
  }
}

// ---------------------------------------------------------------------------
// Mt[b][j][h*96+e] = sum_d Wpt[j][h96+d] * ATt[bh][e][d]
// grid (6, 64), block 256 (16x16, 8x6/thread). K=96.
// ---------------------------------------------------------------------------
__global__ void mt_kernel(const _Float16* __restrict__ Wpt,
                          const _Float16* __restrict__ ATt,
                          _Float16* __restrict__ Mt) {
  const int j0 = blockIdx.x * 128;
  const int bh = blockIdx.y;
  const int b = bh >> 3, h = bh & 7;
  const int tx = threadIdx.x & 15, ty = threadIdx.x >> 4;
  __shared__ float Ws[16][128], Ats[16][96];
  float acc[8][6] = {};

  for (int d0 = 0; d0 < 96; d0 += 16) {
    {
      int jj = threadIdx.x >> 1, s8 = (threadIdx.x & 1) * 8;
      f16x8 v = *(const f16x8*)(Wpt + (size_t)(j0 + jj) * CH + h * HD + d0 + s8);
#pragma unroll
      for (int q = 0; q < 8; ++q) Ws[s8 + q][jj] = (float)v[q];
    }
    if (threadIdx.x < 192) {
      int e = threadIdx.x >> 1, s8 = (threadIdx.x & 1) * 8;
      f16x8 v = *(const f16x8*)(ATt + (size_t)bh * 9216 + (size_t)e * 96 + d0 + s8);
#pragma unroll
      for (int q = 0; q < 8; ++q) Ats[s8 + q][e] = (float)v[q];
    }
    __syncthreads();
#pragma unroll
    for (int kk = 0; kk < 16; ++kk) {
      float a[8], bb[6];
#pragma unroll
      for (int i = 0; i < 8; ++i) a[i] = Ws[kk][ty * 8 + i];
#pragma unroll
      for (int j = 0; j < 6; ++j) bb[j] = Ats[kk][tx * 6 + j];
#pragma unroll
      for (int i = 0; i < 8; ++i)
#pragma unroll
        for (int j = 0; j < 6; ++j)
          acc[i][j] += a[i] * bb[j];
    }
    __syncthreads();
  }

  _Float16* mb = Mt + (size_t)b * CH * CH;
#pragma unroll
  for (int i = 0; i < 8; ++i)
#pragma unroll
    for (int j = 0; j < 6; ++j)
      mb[(size_t)(j0 + ty * 8 + i) * CH + h * HD + tx * 6 + j] = (_Float16)acc[i][j];
}

// ---------------------------------------------------------------------------
extern "C" void kernel_launch(void* const* d_in, const int* in_sizes, int n_in,
                              void* d_out, int out_size, void* d_ws, size_t ws_size,
                              hipStream_t stream) {
  const float* x      = (const float*)d_in[0];
  const float* W_qkv  = (const float*)d_in[1];
  const float* W_proj = (const float*)d_in[2];
  const float* b_proj = (const float*)d_in[3];
  const float* temp   = (const float*)d_in[4];
  float* out = (float*)d_out;
  char* ws = (char*)d_ws;

  _Float16* XT  = (_Float16*)(ws + XT_B);
  _Float16* UT  = (_Float16*)(ws + UT_B);
  float*    SP  = (float*)   (ws + SPART_B);
  _Float16* ATT = (_Float16*)(ws + ATT_B);
  _Float16* MT  = (_Float16*)(ws + MT_B);
  _Float16* PT  = (_Float16*)(ws + PT_B);
  _Float16* G   = (_Float16*)(ws + G_B);
  _Float16* WH  = (_Float16*)(ws + WH_B);
  _Float16* WT  = (_Float16*)(ws + WT_B);
  _Float16* WPT = (_Float16*)(ws + WPT_B);
  float*    INV = (float*)   (ws + INV_B);

  const bool fast = ws_size >= XH_B + XH_BYTES;   // 118.4 MB needed
  _Float16* XH = fast ? (_Float16*)(ws + XH_B) : nullptr;

  const long CC = (long)CH * CH;

  // --- converts / transposes ---
  cvt_f16_kernel<<<(CH * NC3 / 4 + 255) / 256, 256, 0, stream>>>(W_qkv, WH, CH * NC3 / 4);
  transpose_cvt_kernel<<<dim3(CH / 32, SEQ / 32, NB), 256, 0, stream>>>(
      x, XT, XH, SEQ, CH, (long)SEQ * CH, (long)SEQ * CH);
  transpose_cvt_kernel<<<dim3(NC3 / 32, CH / 32, 1), 256, 0, stream>>>(
      W_qkv, WT, nullptr, CH, NC3, 0, 0);
  transpose_cvt_kernel<<<dim3(CH / 32, CH / 32, 1), 256, 0, stream>>>(
      W_proj, WPT, nullptr, CH, CH, 0, 0);

  // --- G_b = xt_b . xt_b^T  (M=N=768, K=4096) ---
  gemm_bt_mfma<false, true, false, true><<<dim3(6, 6, NB), 256, 0, stream>>>(
      XT, XT, nullptr, G, SEQ, SEQ, SEQ, CH, (long)CH * SEQ, (long)CH * SEQ, CC);

  // --- Ut[t][b] = Wt_t . G_b^T  (M=N=768, K=768) ---
  for (int t = 0; t < 2; ++t)
    gemm_bt_mfma<false, true, false, true><<<dim3(6, 6, NB), 256, 0, stream>>>(
        WT + (size_t)t * CC, G, nullptr, UT + (size_t)t * NB * CC,
        CH, CH, CH, CH, 0, CC, CC);

  // --- norms ---
  norm_kernel<<<dim3(16, 6), 128, 0, stream>>>(UT, WT, INV);

  // --- S partials + softmax(+transpose) ---
  spart_kernel<<<dim3(4, 64), 256, 0, stream>>>(WT, UT, SP);
  softmaxT_kernel<<<64, 256, 0, stream>>>(SP, INV, temp, ATT);

  // --- Mt ---
  mt_kernel<<<dim3(6, 64), 256, 0, stream>>>(WPT, ATT, MT);

  // --- Pt_b = Mt_b . Wv^T  (M=N=768, K=768) ---
  gemm_bt_mfma<false, true, false, true><<<dim3(6, 6, NB), 256, 0, stream>>>(
      MT, WH + 2 * CH, nullptr, PT, CH, CH, NC3, CH, CC, 0, CC);

  // --- out_b = x_b . Pt_b^T + bias  (M=4096, N=768, K=768) ---
  if (fast)
    gemm_bt_mfma<false, false, true, true><<<dim3(6, SEQ / 128, NB), 256, 0, stream>>>(
        XH, PT, b_proj, out, CH, CH, CH, CH, (long)SEQ * CH, CC, (long)SEQ * CH);
  else
    gemm_bt_mfma<true, false, true, false><<<dim3(6, SEQ / 128, NB), 256, 0, stream>>>(
        x, PT, b_proj, out, CH, CH, CH, CH, (long)SEQ * CH, CC, (long)SEQ * CH);
}

// Round 5
// 368.572 us; speedup vs baseline: 4.8240x; 1.1240x over previous
//
#include <hip/hip_runtime.h>
#include <math.h>

// Problem constants (b=8, n=4096, c=768, h=8, d=96)
#define NB  8
#define SEQ 4096
#define CH  768
#define NH  8
#define HD  96
#define NC3 2304   // 3*CH

typedef _Float16 f16x8 __attribute__((ext_vector_type(8)));
typedef float    f32x4 __attribute__((ext_vector_type(4)));

// ---------------------------------------------------------------------------
// Workspace layout (BYTE offsets). Total 118,407,168 B — identical to the
// round-4 fast-path requirement (proven available).
// Region 0..50.3MB: XT (fp16 x^T) -> dies after G-split -> UT/SP/ATT/MT/PT.
// Region 50.3..100.7MB: GP (split-K G partials, 37.7MB) -> dies after
//   reduce -> XH (fp16 x row-major, filled just before the out-GEMM).
// ---------------------------------------------------------------------------
static const size_t XT_B   = 0;
static const size_t UT_B   = 0;
static const size_t SP_B   = 18874368;
static const size_t ATT_B  = 28311552;
static const size_t MT_B   = 29491200;
static const size_t PT_B   = 38928384;
static const size_t GP_B   = 50331648;    // 4*8*768*768 halves = 37,748,736 B
static const size_t XH_B   = 50331648;    // 8*4096*768 halves  = 50,331,648 B
static const size_t WH_B   = 100663296;   // 768*2304 halves
static const size_t WT_B   = 104202240;   // 2304*768 halves
static const size_t WPT_B  = 107741184;   // 768*768 halves
static const size_t G_B    = 108920832;   // 8*768*768 halves
static const size_t INV_B  = 118358016;   // 16*768 floats

// ---------------------------------------------------------------------------
// async global->LDS, 16 B per lane (wave-uniform LDS base + lane*16)
// ---------------------------------------------------------------------------
__device__ __forceinline__ void gload16(const void* g, void* l) {
  __builtin_amdgcn_global_load_lds(
      (const __attribute__((address_space(1))) void*)g,
      (__attribute__((address_space(3))) void*)l, 16, 0, 0);
}

// ---------------------------------------------------------------------------
// Elementwise fp32 -> fp16 convert (vectorized by 4)
// ---------------------------------------------------------------------------
__global__ void cvt_f16_kernel(const float* __restrict__ in,
                               _Float16* __restrict__ out, int n4) {
  int i = blockIdx.x * blockDim.x + threadIdx.x;
  if (i < n4) {
    float4 v = *(const float4*)(in + (size_t)i * 4);
    _Float16* o = out + (size_t)i * 4;
    o[0] = (_Float16)v.x; o[1] = (_Float16)v.y;
    o[2] = (_Float16)v.z; o[3] = (_Float16)v.w;
  }
}

// ---------------------------------------------------------------------------
// Tiled transpose+convert: fp32 [R][C] -> fp16 [C][R], batched.
// grid (C/32, R/32, batch), block 256.
// ---------------------------------------------------------------------------
__global__ void transpose_cvt_kernel(const float* __restrict__ in,
                                     _Float16* __restrict__ outT,
                                     int R, int C, long sIn, long sOut) {
  __shared__ float t[32][33];
  const int b = blockIdx.z;
  const int c0 = blockIdx.x * 32, r0 = blockIdx.y * 32;
  const int tx = threadIdx.x & 31, ty = threadIdx.x >> 5;   // ty 0..7
  const float* ib = in + (size_t)b * sIn;
  _Float16* ob = outT + (size_t)b * sOut;
#pragma unroll
  for (int k = 0; k < 4; ++k)
    t[ty + 8 * k][tx] = ib[(size_t)(r0 + ty + 8 * k) * C + c0 + tx];
  __syncthreads();
#pragma unroll
  for (int k = 0; k < 4; ++k)
    ob[(size_t)(c0 + ty + 8 * k) * R + r0 + tx] = (_Float16)t[tx][ty + 8 * k];
}

// ---------------------------------------------------------------------------
// MFMA GEMM:  C = A(MxK) * B(NxK)^T (+ bias over N), fp16 in, fp16/fp32 out.
// 128x128 tile, BK=32, 4 waves, 4x4 16x16x32 fragments per wave.
// 2-phase double-buffered global_load_lds staging with counted vmcnt(4)
// and raw s_barrier (keeps next-tile loads in flight across the MFMA phase).
// Source-side XOR swizzle (slot ^ ((row>>1)&3)), same XOR on ds_read.
// grid.z decomposition: bat = z % zdiv, chk = z / zdiv; operand base =
//   base + bat*sX + chk*xCS  (supports split-K and fused multi-GEMM).
// Requires M%128==0, N%128==0, K%32==0.
// ---------------------------------------------------------------------------
template<bool FP16OUT, bool BIAS>
__global__ __launch_bounds__(256) void gemm_bt_mfma(
    const _Float16* __restrict__ Ap, const _Float16* __restrict__ Bp,
    const float* __restrict__ bias, void* __restrict__ Cp,
    int K, int lda, int ldb, int ldc,
    long sA, long sB, long sC, int zdiv, long aCS, long bCS, long cCS) {
  __shared__ __align__(16) _Float16 ldsA[2][128 * 32];
  __shared__ __align__(16) _Float16 ldsB[2][128 * 32];

  const int z = blockIdx.z;
  const int bat = z % zdiv, chk = z / zdiv;
  const _Float16* A = Ap + (size_t)bat * sA + (size_t)chk * aCS;
  const _Float16* B = Bp + (size_t)bat * sB + (size_t)chk * bCS;
  const size_t cOff = (size_t)bat * sC + (size_t)chk * cCS;

  const int row0 = blockIdx.y * 128, col0 = blockIdx.x * 128;
  const int tid = threadIdx.x;
  const int l = tid & 63, w = tid >> 6;
  const int lo = l & 15, hi = l >> 4;
  const int wr = w >> 1, wc = w & 1;

  // staging: wave w covers rows 32w..32w+31, two 16-row gload16 calls
  const int rw = 32 * w;
  const int lr = l >> 2;        // row within 16-row group
  const int ls = l & 3;         // 16B slot within 64B row

  f32x4 acc[4][4];
#pragma unroll
  for (int i = 0; i < 4; ++i)
#pragma unroll
    for (int j = 0; j < 4; ++j)
      acc[i][j] = (f32x4){0.f, 0.f, 0.f, 0.f};

  auto STAGE = [&](int hb, int k0) {
#pragma unroll
    for (int q = 0; q < 2; ++q) {
      const int r = rw + 16 * q + lr;
      const int ck = ls ^ ((r >> 1) & 3);     // source-side swizzle
      gload16(A + (size_t)(row0 + r) * lda + k0 + 8 * ck,
              &ldsA[hb][(rw + 16 * q) * 32]);
      gload16(B + (size_t)(col0 + r) * ldb + k0 + 8 * ck,
              &ldsB[hb][(rw + 16 * q) * 32]);
    }
  };

  STAGE(0, 0);
  const int nt = K / 32;
  int cur = 0;
  for (int t = 0; t < nt; ++t) {
    if (t + 1 < nt) {
      STAGE(cur ^ 1, 32 * (t + 1));
      asm volatile("s_waitcnt vmcnt(4)" : : : "memory");   // cur's 4 done
    } else {
      asm volatile("s_waitcnt vmcnt(0)" : : : "memory");
    }
    __builtin_amdgcn_s_barrier();          // raw: does NOT drain vmcnt

    f16x8 a[4], b[4];
#pragma unroll
    for (int mi = 0; mi < 4; ++mi) {
      int Ra = 64 * wr + 16 * mi + lo;
      a[mi] = *(const f16x8*)&ldsA[cur][Ra * 32 + (hi ^ ((Ra >> 1) & 3)) * 8];
    }
#pragma unroll
    for (int ni = 0; ni < 4; ++ni) {
      int Rb = 64 * wc + 16 * ni + lo;
      b[ni] = *(const f16x8*)&ldsB[cur][Rb * 32 + (hi ^ ((Rb >> 1) & 3)) * 8];
    }
#pragma unroll
    for (int mi = 0; mi < 4; ++mi)
#pragma unroll
      for (int ni = 0; ni < 4; ++ni)
        acc[mi][ni] = __builtin_amdgcn_mfma_f32_16x16x32_f16(
            a[mi], b[ni], acc[mi][ni], 0, 0, 0);

    __builtin_amdgcn_s_barrier();          // all reads of [cur] done
    cur ^= 1;
  }

  // epilogue: D[row][col], col = lane&15, row = 4*(lane>>4)+reg
#pragma unroll
  for (int ni = 0; ni < 4; ++ni) {
    const int col = col0 + 64 * wc + 16 * ni + lo;
    float bv = 0.f;
    if constexpr (BIAS) bv = bias[col];
#pragma unroll
    for (int mi = 0; mi < 4; ++mi) {
      const int rowb = row0 + 64 * wr + 16 * mi + 4 * hi;
#pragma unroll
      for (int r = 0; r < 4; ++r) {
        float v = acc[mi][ni][r] + bv;
        if constexpr (FP16OUT)
          ((_Float16*)Cp)[cOff + (size_t)(rowb + r) * ldc + col] = (_Float16)v;
        else
          ((float*)Cp)[cOff + (size_t)(rowb + r) * ldc + col] = v;
      }
    }
  }
}

// ---------------------------------------------------------------------------
// Reduce split-K partials: G[e] = sum_c GP[c][e], fp16 in/out, fp32 accum.
// ---------------------------------------------------------------------------
__global__ void reduce_g_kernel(const _Float16* __restrict__ GP,
                                _Float16* __restrict__ G) {
  const size_t i = ((size_t)blockIdx.x * 256 + threadIdx.x) * 8;
  const size_t stride = (size_t)NB * CH * CH;
  f16x8 c0 = *(const f16x8*)(GP + i);
  f16x8 c1 = *(const f16x8*)(GP + stride + i);
  f16x8 c2 = *(const f16x8*)(GP + 2 * stride + i);
  f16x8 c3 = *(const f16x8*)(GP + 3 * stride + i);
  f16x8 o;
#pragma unroll
  for (int q = 0; q < 8; ++q)
    o[q] = (_Float16)(((float)c0[q] + (float)c1[q]) +
                      ((float)c2[q] + (float)c3[q]));
  *(f16x8*)(G + i) = o;
}

// ---------------------------------------------------------------------------
// Norms: INV[t][b][c] = 1/max(sqrt(sum_i Ut[t][b][c][i]*Wt[t*768+c][i]),eps)
// grid (16, 6), block 128.
// ---------------------------------------------------------------------------
__global__ void norm_kernel(const _Float16* __restrict__ Ut,
                            const _Float16* __restrict__ Wt,
                            float* __restrict__ INVv) {
  const int z = blockIdx.x;           // t*8+b
  const int t = z >> 3;
  const int c = blockIdx.y * 128 + threadIdx.x;
  const _Float16* u = Ut + ((size_t)z * CH + c) * CH;
  const _Float16* wv = Wt + ((size_t)(t * CH + c)) * CH;
  float s = 0.f;
  for (int i = 0; i < CH; i += 8) {
    f16x8 uv = *(const f16x8*)(u + i);
    f16x8 wq = *(const f16x8*)(wv + i);
#pragma unroll
    for (int q = 0; q < 8; ++q) s += (float)uv[q] * (float)wq[q];
  }
  s = fmaxf(s, 0.f);
  INVv[(size_t)z * CH + c] = 1.0f / fmaxf(sqrtf(s), 1e-12f);
}

// ---------------------------------------------------------------------------
// S partial: Spart[chunk][bh][d][e] = sum_{i in chunk} Wt[h96+d][i]*Ut1[b][h96+e][i]
// grid (4, 64), block 256 (16x16, 6x6/thread).
// ---------------------------------------------------------------------------
__global__ void spart_kernel(const _Float16* __restrict__ Wt,
                             const _Float16* __restrict__ Ut,
                             float* __restrict__ Spart) {
  const int chunk = blockIdx.x, bh = blockIdx.y;
  const int b = bh >> 3, h = bh & 7;
  const int tx = threadIdx.x & 15, ty = threadIdx.x >> 4;
  __shared__ float As[16][96], Bs[16][96];
  const int i0 = chunk * 192;
  float acc[6][6] = {};

  for (int kk0 = 0; kk0 < 192; kk0 += 16) {
    if (threadIdx.x < 192) {
      int row = threadIdx.x >> 1, s8 = (threadIdx.x & 1) * 8;
      f16x8 av = *(const f16x8*)(Wt + (size_t)(h * HD + row) * CH + i0 + kk0 + s8);
      f16x8 bv = *(const f16x8*)(Ut + ((size_t)(8 + b) * CH + h * HD + row) * CH + i0 + kk0 + s8);
#pragma unroll
      for (int q = 0; q < 8; ++q) {
        As[s8 + q][row] = (float)av[q];
        Bs[s8 + q][row] = (float)bv[q];
      }
    }
    __syncthreads();
#pragma unroll
    for (int kk = 0; kk < 16; ++kk) {
      float a[6], bb[6];
#pragma unroll
      for (int j = 0; j < 6; ++j) { a[j] = As[kk][ty * 6 + j]; bb[j] = Bs[kk][tx * 6 + j]; }
#pragma unroll
      for (int i = 0; i < 6; ++i)
#pragma unroll
        for (int j = 0; j < 6; ++j)
          acc[i][j] += a[i] * bb[j];
    }
    __syncthreads();
  }

  float* o = Spart + ((size_t)chunk * 64 + bh) * 9216;
#pragma unroll
  for (int i = 0; i < 6; ++i)
#pragma unroll
    for (int j = 0; j < 6; ++j)
      o[(size_t)(ty * 6 + i) * 96 + tx * 6 + j] = acc[i][j];
}

// ---------------------------------------------------------------------------
// Combine partials + scale + softmax over e + transposed fp16 write.
// grid 64, block 256.
// ---------------------------------------------------------------------------
__global__ void softmaxT_kernel(const float* __restrict__ Spart,
                                const float* __restrict__ INVv,
                                const float* __restrict__ temp,
                                _Float16* __restrict__ ATt) {
  const int bh = blockIdx.x;
  const int b = bh >> 3, h = bh & 7;
  __shared__ float S[96][97];
  const float tv = temp[h];
  const float* iq = INVv + (size_t)b * CH + h * HD;
  const float* ik = INVv + (size_t)(8 + b) * CH + h * HD;

  for (int i = threadIdx.x; i < 9216; i += 256) {
    float s = 0.f;
#pragma unroll
    for (int c = 0; c < 4; ++c) s += Spart[((size_t)c * 64 + bh) * 9216 + i];
    int d = i / 96, e = i % 96;
    S[d][e] = s * iq[d] * ik[e] * tv;
  }
  __syncthreads();

  if (threadIdx.x < 96) {
    const int d = threadIdx.x;
    float mx = -INFINITY;
    for (int e = 0; e < 96; ++e) mx = fmaxf(mx, S[d][e]);
    float sum = 0.f;
    for (int e = 0; e < 96; ++e) {
      float ex = expf(S[d][e] - mx);
      S[d][e] = ex;
      sum += ex;
    }
    float inv = 1.0f / sum;
    _Float16* ab = ATt + (size_t)bh * 9216;
    for (int e = 0; e < 96; ++e)
      ab[(size_t)e * 96 + d] = (_Float16)(S[d][e] * inv);
  }
}

// ---------------------------------------------------------------------------
// Mt[b][j][h*96+e] = sum_d Wpt[j][h96+d] * ATt[bh][e][d]
// grid (6, 64), block 256 (16x16, 8x6/thread). K=96.
// ---------------------------------------------------------------------------
__global__ void mt_kernel(const _Float16* __restrict__ Wpt,
                          const _Float16* __restrict__ ATt,
                          _Float16* __restrict__ Mt) {
  const int j0 = blockIdx.x * 128;
  const int bh = blockIdx.y;
  const int b = bh >> 3, h = bh & 7;
  const int tx = threadIdx.x & 15, ty = threadIdx.x >> 4;
  __shared__ float Ws[16][128], Ats[16][96];
  float acc[8][6] = {};

  for (int d0 = 0; d0 < 96; d0 += 16) {
    {
      int jj = threadIdx.x >> 1, s8 = (threadIdx.x & 1) * 8;
      f16x8 v = *(const f16x8*)(Wpt + (size_t)(j0 + jj) * CH + h * HD + d0 + s8);
#pragma unroll
      for (int q = 0; q < 8; ++q) Ws[s8 + q][jj] = (float)v[q];
    }
    if (threadIdx.x < 192) {
      int e = threadIdx.x >> 1, s8 = (threadIdx.x & 1) * 8;
      f16x8 v = *(const f16x8*)(ATt + (size_t)bh * 9216 + (size_t)e * 96 + d0 + s8);
#pragma unroll
      for (int q = 0; q < 8; ++q) Ats[s8 + q][e] = (float)v[q];
    }
    __syncthreads();
#pragma unroll
    for (int kk = 0; kk < 16; ++kk) {
      float a[8], bb[6];
#pragma unroll
      for (int i = 0; i < 8; ++i) a[i] = Ws[kk][ty * 8 + i];
#pragma unroll
      for (int j = 0; j < 6; ++j) bb[j] = Ats[kk][tx * 6 + j];
#pragma unroll
      for (int i = 0; i < 8; ++i)
#pragma unroll
        for (int j = 0; j < 6; ++j)
          acc[i][j] += a[i] * bb[j];
    }
    __syncthreads();
  }

  _Float16* mb = Mt + (size_t)b * CH * CH;
#pragma unroll
  for (int i = 0; i < 8; ++i)
#pragma unroll
    for (int j = 0; j < 6; ++j)
      mb[(size_t)(j0 + ty * 8 + i) * CH + h * HD + tx * 6 + j] = (_Float16)acc[i][j];
}

// ---------------------------------------------------------------------------
extern "C" void kernel_launch(void* const* d_in, const int* in_sizes, int n_in,
                              void* d_out, int out_size, void* d_ws, size_t ws_size,
                              hipStream_t stream) {
  const float* x      = (const float*)d_in[0];
  const float* W_qkv  = (const float*)d_in[1];
  const float* W_proj = (const float*)d_in[2];
  const float* b_proj = (const float*)d_in[3];
  const float* temp   = (const float*)d_in[4];
  float* out = (float*)d_out;
  char* ws = (char*)d_ws;

  _Float16* XT  = (_Float16*)(ws + XT_B);
  _Float16* UT  = (_Float16*)(ws + UT_B);
  float*    SP  = (float*)   (ws + SP_B);
  _Float16* ATT = (_Float16*)(ws + ATT_B);
  _Float16* MT  = (_Float16*)(ws + MT_B);
  _Float16* PT  = (_Float16*)(ws + PT_B);
  _Float16* GP  = (_Float16*)(ws + GP_B);
  _Float16* XH  = (_Float16*)(ws + XH_B);
  _Float16* WH  = (_Float16*)(ws + WH_B);
  _Float16* WT  = (_Float16*)(ws + WT_B);
  _Float16* WPT = (_Float16*)(ws + WPT_B);
  _Float16* G   = (_Float16*)(ws + G_B);
  float*    INV = (float*)   (ws + INV_B);

  const long CC = (long)CH * CH;           // 589824
  const long SC = (long)SEQ * CH;          // 3145728

  // --- weight converts / transposes, x -> XT ---
  cvt_f16_kernel<<<(CH * NC3 / 4 + 255) / 256, 256, 0, stream>>>(
      W_qkv, WH, CH * NC3 / 4);
  transpose_cvt_kernel<<<dim3(CH / 32, SEQ / 32, NB), 256, 0, stream>>>(
      x, XT, SEQ, CH, SC, SC);
  transpose_cvt_kernel<<<dim3(NC3 / 32, CH / 32, 1), 256, 0, stream>>>(
      W_qkv, WT, CH, NC3, 0, 0);
  transpose_cvt_kernel<<<dim3(CH / 32, CH / 32, 1), 256, 0, stream>>>(
      W_proj, WPT, CH, CH, 0, 0);

  // --- G partials: GP[chk][b] = XT_b[:, chk*1024:+1024] . (same)^T ---
  gemm_bt_mfma<true, false><<<dim3(6, 6, 32), 256, 0, stream>>>(
      XT, XT, nullptr, GP, 1024, SEQ, SEQ, CH,
      (long)CH * SEQ, (long)CH * SEQ, CC, NB, 1024, 1024, (long)NB * CC);

  // --- reduce partials -> G (fp16) ---
  reduce_g_kernel<<<(int)(NB * CC / 8 / 256), 256, 0, stream>>>(GP, G);

  // --- U fused over t: UT[t][b] = Wt_t . G_b^T  (z = t*8+b) ---
  gemm_bt_mfma<true, false><<<dim3(6, 6, 16), 256, 0, stream>>>(
      WT, G, nullptr, UT, CH, CH, CH, CH,
      0, CC, CC, NB, CC, 0, (long)NB * CC);

  // --- norms ---
  norm_kernel<<<dim3(16, 6), 128, 0, stream>>>(UT, WT, INV);

  // --- S partials + softmax(+transpose) ---
  spart_kernel<<<dim3(4, 64), 256, 0, stream>>>(WT, UT, SP);
  softmaxT_kernel<<<64, 256, 0, stream>>>(SP, INV, temp, ATT);

  // --- Mt ---
  mt_kernel<<<dim3(6, 64), 256, 0, stream>>>(WPT, ATT, MT);

  // --- Pt_b = Mt_b . Wv^T  (Wv rows via WH, ldb = 2304) ---
  gemm_bt_mfma<true, false><<<dim3(6, 6, NB), 256, 0, stream>>>(
      MT, WH + 2 * CH, nullptr, PT, CH, CH, NC3, CH,
      CC, 0, CC, NB, 0, 0, 0);

  // --- x -> XH (GP dead now) ---
  cvt_f16_kernel<<<(int)(NB * SC / 4 / 256), 256, 0, stream>>>(
      x, XH, (int)(NB * SC / 4));

  // --- out_b = XH_b . Pt_b^T + bias  (M=4096, N=768, K=768, fp32 C) ---
  gemm_bt_mfma<false, true><<<dim3(6, SEQ / 128, NB), 256, 0, stream>>>(
      XH, PT, b_proj, out, CH, CH, CH, CH,
      SC, CC, SC, NB, 0, 0, 0);
}

// Round 6
// 265.170 us; speedup vs baseline: 6.7051x; 1.3899x over previous
//
#include <hip/hip_runtime.h>
#include <math.h>

// Problem constants (b=8, n=4096, c=768, h=8, d=96)
#define NB  8
#define SEQ 4096
#define CH  768
#define NH  8
#define HD  96
#define NC3 2304   // 3*CH

typedef _Float16 f16x8 __attribute__((ext_vector_type(8)));
typedef float    f32x4 __attribute__((ext_vector_type(4)));

// ---------------------------------------------------------------------------
// Workspace layout (BYTE offsets). Total 118,407,168 B (proven available).
// ---------------------------------------------------------------------------
static const size_t XT_B   = 0;           // fp16 x^T [b][c][n]; dies after G
static const size_t UT_B   = 0;           // overlays XT
static const size_t ATT_B  = 28311552;
static const size_t MT_B   = 29491200;
static const size_t PT_B   = 38928384;
static const size_t GP_B   = 50331648;    // G partials; dies after reduce
static const size_t XH_B   = 50331648;    // fp16 x row-major (fills after GP)
static const size_t WH_B   = 100663296;
static const size_t WT_B   = 104202240;
static const size_t WPT_B  = 107741184;
static const size_t G_B    = 108920832;
static const size_t INV_B  = 118358016;

// ---------------------------------------------------------------------------
// async global->LDS, 16 B per lane (wave-uniform LDS base + lane*16)
// ---------------------------------------------------------------------------
__device__ __forceinline__ void gload16(const void* g, void* l) {
  __builtin_amdgcn_global_load_lds(
      (const __attribute__((address_space(1))) void*)g,
      (__attribute__((address_space(3))) void*)l, 16, 0, 0);
}

// ---------------------------------------------------------------------------
// Elementwise fp32 -> fp16 convert
// ---------------------------------------------------------------------------
__global__ void cvt_f16_kernel(const float* __restrict__ in,
                               _Float16* __restrict__ out, int n4) {
  int i = blockIdx.x * blockDim.x + threadIdx.x;
  if (i < n4) {
    float4 v = *(const float4*)(in + (size_t)i * 4);
    _Float16* o = out + (size_t)i * 4;
    o[0] = (_Float16)v.x; o[1] = (_Float16)v.y;
    o[2] = (_Float16)v.z; o[3] = (_Float16)v.w;
  }
}

// ---------------------------------------------------------------------------
// Tiled transpose+convert: fp32 [R][C] -> fp16 [C][R], batched.
// ---------------------------------------------------------------------------
__global__ void transpose_cvt_kernel(const float* __restrict__ in,
                                     _Float16* __restrict__ outT,
                                     int R, int C, long sIn, long sOut) {
  __shared__ float t[32][33];
  const int b = blockIdx.z;
  const int c0 = blockIdx.x * 32, r0 = blockIdx.y * 32;
  const int tx = threadIdx.x & 31, ty = threadIdx.x >> 5;
  const float* ib = in + (size_t)b * sIn;
  _Float16* ob = outT + (size_t)b * sOut;
#pragma unroll
  for (int k = 0; k < 4; ++k)
    t[ty + 8 * k][tx] = ib[(size_t)(r0 + ty + 8 * k) * C + c0 + tx];
  __syncthreads();
#pragma unroll
  for (int k = 0; k < 4; ++k)
    ob[(size_t)(c0 + ty + 8 * k) * R + r0 + tx] = (_Float16)t[tx][ty + 8 * k];
}

// ---------------------------------------------------------------------------
// MFMA GEMM:  C = A(MxK) * B(NxK)^T (+ bias), fp16 in, fp16/fp32 out.
// 128x128 tile, BK=32, 2-phase dbuf global_load_lds, counted vmcnt(4),
// raw s_barrier. 1D grid with XCD-chunk swizzle (requires nwg%8==0).
// TRI: grid tile index -> upper-triangle (ti<=tj) pair of a 6x6 tiling
// (symmetric output; only 21 of 36 tiles computed).
// ---------------------------------------------------------------------------
template<bool FP16OUT, bool BIAS, bool TRI>
__global__ __launch_bounds__(256) void gemm_bt_mfma(
    const _Float16* __restrict__ Ap, const _Float16* __restrict__ Bp,
    const float* __restrict__ bias, void* __restrict__ Cp,
    int K, int lda, int ldb, int ldc,
    long sA, long sB, long sC, int zdiv, long aCS, long bCS, long cCS,
    int gx, int gy) {
  __shared__ __align__(16) _Float16 ldsA[2][128 * 32];
  __shared__ __align__(16) _Float16 ldsB[2][128 * 32];

  // XCD-aware swizzle: contiguous work chunk per XCD
  const int nwg = gridDim.x;
  const int lid = blockIdx.x;
  const int wg = (lid & 7) * (nwg >> 3) + (lid >> 3);
  int bx, by, z;
  if constexpr (TRI) {
    int tt = wg % 21; z = wg / 21;
    int ti = 0, rem = tt;
    while (rem >= 6 - ti) { rem -= 6 - ti; ++ti; }
    by = ti; bx = ti + rem;
  } else {
    bx = wg % gx; int r2 = wg / gx; by = r2 % gy; z = r2 / gy;
  }
  const int bat = z % zdiv, chk = z / zdiv;
  const _Float16* A = Ap + (size_t)bat * sA + (size_t)chk * aCS;
  const _Float16* B = Bp + (size_t)bat * sB + (size_t)chk * bCS;
  const size_t cOff = (size_t)bat * sC + (size_t)chk * cCS;

  const int row0 = by * 128, col0 = bx * 128;
  const int tid = threadIdx.x;
  const int l = tid & 63, w = tid >> 6;
  const int lo = l & 15, hi = l >> 4;
  const int wr = w >> 1, wc = w & 1;

  const int rw = 32 * w;
  const int lr = l >> 2;
  const int ls = l & 3;

  f32x4 acc[4][4];
#pragma unroll
  for (int i = 0; i < 4; ++i)
#pragma unroll
    for (int j = 0; j < 4; ++j)
      acc[i][j] = (f32x4){0.f, 0.f, 0.f, 0.f};

  auto STAGE = [&](int hb, int k0) {
#pragma unroll
    for (int q = 0; q < 2; ++q) {
      const int r = rw + 16 * q + lr;
      const int ck = ls ^ ((r >> 1) & 3);
      gload16(A + (size_t)(row0 + r) * lda + k0 + 8 * ck,
              &ldsA[hb][(rw + 16 * q) * 32]);
      gload16(B + (size_t)(col0 + r) * ldb + k0 + 8 * ck,
              &ldsB[hb][(rw + 16 * q) * 32]);
    }
  };

  STAGE(0, 0);
  const int nt = K / 32;
  int cur = 0;
  for (int t = 0; t < nt; ++t) {
    if (t + 1 < nt) {
      STAGE(cur ^ 1, 32 * (t + 1));
      asm volatile("s_waitcnt vmcnt(4)" : : : "memory");
    } else {
      asm volatile("s_waitcnt vmcnt(0)" : : : "memory");
    }
    __builtin_amdgcn_s_barrier();

    f16x8 a[4], b[4];
#pragma unroll
    for (int mi = 0; mi < 4; ++mi) {
      int Ra = 64 * wr + 16 * mi + lo;
      a[mi] = *(const f16x8*)&ldsA[cur][Ra * 32 + (hi ^ ((Ra >> 1) & 3)) * 8];
    }
#pragma unroll
    for (int ni = 0; ni < 4; ++ni) {
      int Rb = 64 * wc + 16 * ni + lo;
      b[ni] = *(const f16x8*)&ldsB[cur][Rb * 32 + (hi ^ ((Rb >> 1) & 3)) * 8];
    }
#pragma unroll
    for (int mi = 0; mi < 4; ++mi)
#pragma unroll
      for (int ni = 0; ni < 4; ++ni)
        acc[mi][ni] = __builtin_amdgcn_mfma_f32_16x16x32_f16(
            a[mi], b[ni], acc[mi][ni], 0, 0, 0);

    __builtin_amdgcn_s_barrier();
    cur ^= 1;
  }

#pragma unroll
  for (int ni = 0; ni < 4; ++ni) {
    const int col = col0 + 64 * wc + 16 * ni + lo;
    float bv = 0.f;
    if constexpr (BIAS) bv = bias[col];
#pragma unroll
    for (int mi = 0; mi < 4; ++mi) {
      const int rowb = row0 + 64 * wr + 16 * mi + 4 * hi;
#pragma unroll
      for (int r = 0; r < 4; ++r) {
        float v = acc[mi][ni][r] + bv;
        if constexpr (FP16OUT)
          ((_Float16*)Cp)[cOff + (size_t)(rowb + r) * ldc + col] = (_Float16)v;
        else
          ((float*)Cp)[cOff + (size_t)(rowb + r) * ldc + col] = v;
      }
    }
  }
}

// ---------------------------------------------------------------------------
// Reduce 4 split-K chunks of the 21 upper-tri tiles and mirror to full G.
// grid (21, 8), block 256.
// ---------------------------------------------------------------------------
__global__ void reduce_mirror_kernel(const _Float16* __restrict__ GP,
                                     _Float16* __restrict__ G) {
  const int t = blockIdx.x, b = blockIdx.y;
  int ti = 0, rem = t;
  while (rem >= 6 - ti) { rem -= 6 - ti; ++ti; }
  const int tj = ti + rem;
  const int i0 = ti * 128, j0 = tj * 128;
  const int tx = threadIdx.x & 31, ty = threadIdx.x >> 5;
  __shared__ float lds[32][33];
  const size_t cs = (size_t)NB * CH * CH;
  const _Float16* gp = GP + (size_t)b * CH * CH;
  _Float16* g = G + (size_t)b * CH * CH;

  for (int st = 0; st < 16; ++st) {
    const int sr = i0 + (st >> 2) * 32, sc = j0 + (st & 3) * 32;
    __syncthreads();
#pragma unroll
    for (int k = 0; k < 4; ++k) {
      const int r = ty + 8 * k;
      const size_t off = (size_t)(sr + r) * CH + sc + tx;
      float v = ((float)gp[off] + (float)gp[cs + off]) +
                ((float)gp[2 * cs + off] + (float)gp[3 * cs + off]);
      lds[r][tx] = v;
      g[off] = (_Float16)v;
    }
    if (ti != tj) {
      __syncthreads();
#pragma unroll
      for (int k = 0; k < 4; ++k) {
        const int r = ty + 8 * k;
        g[(size_t)(sc + r) * CH + sr + tx] = (_Float16)lds[tx][r];
      }
    }
  }
}

// ---------------------------------------------------------------------------
// Norms: INV[t*8+b][c] = 1/max(sqrt(sum_i Ut[t][b][c][i]*Wt[t*768+c][i]),eps)
// ---------------------------------------------------------------------------
__global__ void norm_kernel(const _Float16* __restrict__ Ut,
                            const _Float16* __restrict__ Wt,
                            float* __restrict__ INVv) {
  const int z = blockIdx.x;
  const int t = z >> 3;
  const int c = blockIdx.y * 128 + threadIdx.x;
  const _Float16* u = Ut + ((size_t)z * CH + c) * CH;
  const _Float16* wv = Wt + ((size_t)(t * CH + c)) * CH;
  float s = 0.f;
  for (int i = 0; i < CH; i += 8) {
    f16x8 uv = *(const f16x8*)(u + i);
    f16x8 wq = *(const f16x8*)(wv + i);
#pragma unroll
    for (int q = 0; q < 8; ++q) s += (float)uv[q] * (float)wq[q];
  }
  s = fmaxf(s, 0.f);
  INVv[(size_t)z * CH + c] = 1.0f / fmaxf(sqrtf(s), 1e-12f);
}

// ---------------------------------------------------------------------------
// Fused S = Wq-rows . Ut1-rows^T (96x96, K=768) via MFMA, scale, softmax
// over e, transposed fp16 ATt write. grid 64 (bh), 256 threads (4 waves,
// 2Mx2N, 3x3 16x16x32 frags each). Combined [A;B] 192-row LDS stack.
// ---------------------------------------------------------------------------
__global__ __launch_bounds__(256) void sattn_kernel(
    const _Float16* __restrict__ WT_, const _Float16* __restrict__ UT_,
    const float* __restrict__ INVv, const float* __restrict__ temp,
    _Float16* __restrict__ ATt) {
  const int bh = blockIdx.x;
  const int b = bh >> 3, h = bh & 7;
  __shared__ __align__(16) _Float16 lds[2][192 * 32];
  __shared__ float S[96][100];

  const int tid = threadIdx.x;
  const int l = tid & 63, w = tid >> 6;
  const int lo = l & 15, hi = l >> 4;
  const int wr = w >> 1, wc = w & 1;
  const int lr = l >> 2, lq = l & 3;

  const _Float16* Abase = WT_ + (size_t)(h * HD) * CH;                     // Wq rows d
  const _Float16* Bbase = UT_ + ((size_t)(8 + b) * CH + h * HD) * CH;      // Ut1 rows e

  f32x4 acc[3][3];
#pragma unroll
  for (int i = 0; i < 3; ++i)
#pragma unroll
    for (int j = 0; j < 3; ++j)
      acc[i][j] = (f32x4){0.f, 0.f, 0.f, 0.f};

  auto STAGE = [&](int hb, int k0) {
#pragma unroll
    for (int c = 0; c < 3; ++c) {
      const int group = w * 3 + c;            // 0..11; 0-5 = A, 6-11 = B
      const int row = group * 16 + lr;        // 0..191
      const int ck = lq ^ ((row >> 1) & 3);
      const _Float16* src = (row < 96)
          ? Abase + (size_t)row * CH + k0 + 8 * ck
          : Bbase + (size_t)(row - 96) * CH + k0 + 8 * ck;
      gload16(src, &lds[hb][group * 512]);
    }
  };

  STAGE(0, 0);
  int cur = 0;
  for (int t = 0; t < 24; ++t) {
    if (t + 1 < 24) {
      STAGE(cur ^ 1, 32 * (t + 1));
      asm volatile("s_waitcnt vmcnt(3)" : : : "memory");
    } else {
      asm volatile("s_waitcnt vmcnt(0)" : : : "memory");
    }
    __builtin_amdgcn_s_barrier();

    f16x8 a[3], bb[3];
#pragma unroll
    for (int mi = 0; mi < 3; ++mi) {
      const int Ra = 48 * wr + 16 * mi + lo;
      a[mi] = *(const f16x8*)&lds[cur][Ra * 32 + (hi ^ ((Ra >> 1) & 3)) * 8];
    }
#pragma unroll
    for (int ni = 0; ni < 3; ++ni) {
      const int Rb = 96 + 48 * wc + 16 * ni + lo;
      bb[ni] = *(const f16x8*)&lds[cur][Rb * 32 + (hi ^ ((Rb >> 1) & 3)) * 8];
    }
#pragma unroll
    for (int mi = 0; mi < 3; ++mi)
#pragma unroll
      for (int ni = 0; ni < 3; ++ni)
        acc[mi][ni] = __builtin_amdgcn_mfma_f32_16x16x32_f16(
            a[mi], bb[ni], acc[mi][ni], 0, 0, 0);

    __builtin_amdgcn_s_barrier();
    cur ^= 1;
  }

  // scale by invq[d]*invk[e]*temp[h], write S to LDS
  const float tv = temp[h];
  const float* iq = INVv + (size_t)b * CH + h * HD;
  const float* ik = INVv + (size_t)(8 + b) * CH + h * HD;
#pragma unroll
  for (int ni = 0; ni < 3; ++ni) {
    const int col = 48 * wc + 16 * ni + lo;
    const float ikv = ik[col];
#pragma unroll
    for (int mi = 0; mi < 3; ++mi) {
      const int rb = 48 * wr + 16 * mi + 4 * hi;
#pragma unroll
      for (int r = 0; r < 4; ++r)
        S[rb + r][col] = acc[mi][ni][r] * iq[rb + r] * ikv * tv;
    }
  }
  __syncthreads();

  // wave-parallel softmax: 16 groups of 16 lanes, 6 rows each, 6 e/lane
  const int g16 = tid >> 4, l16 = tid & 15;
  _Float16* ab = ATt + (size_t)bh * 9216;
#pragma unroll
  for (int it = 0; it < 6; ++it) {
    const int d = g16 + 16 * it;
    float v[6];
    float mx = -INFINITY;
#pragma unroll
    for (int j = 0; j < 6; ++j) { v[j] = S[d][l16 * 6 + j]; mx = fmaxf(mx, v[j]); }
#pragma unroll
    for (int m = 1; m < 16; m <<= 1) mx = fmaxf(mx, __shfl_xor(mx, m, 16));
    float sum = 0.f;
#pragma unroll
    for (int j = 0; j < 6; ++j) { v[j] = __expf(v[j] - mx); sum += v[j]; }
#pragma unroll
    for (int m = 1; m < 16; m <<= 1) sum += __shfl_xor(sum, m, 16);
    const float inv = 1.0f / sum;
#pragma unroll
    for (int j = 0; j < 6; ++j)
      ab[(size_t)(l16 * 6 + j) * 96 + d] = (_Float16)(v[j] * inv);
  }
}

// ---------------------------------------------------------------------------
// Mt[b][j][h*96+e] = sum_d Wpt[j][h96+d] * ATt[bh][e][d]
// ---------------------------------------------------------------------------
__global__ void mt_kernel(const _Float16* __restrict__ Wpt,
                          const _Float16* __restrict__ ATt,
                          _Float16* __restrict__ Mt) {
  const int j0 = blockIdx.x * 128;
  const int bh = blockIdx.y;
  const int b = bh >> 3, h = bh & 7;
  const int tx = threadIdx.x & 15, ty = threadIdx.x >> 4;
  __shared__ float Ws[16][128], Ats[16][96];
  float acc[8][6] = {};

  for (int d0 = 0; d0 < 96; d0 += 16) {
    {
      int jj = threadIdx.x >> 1, s8 = (threadIdx.x & 1) * 8;
      f16x8 v = *(const f16x8*)(Wpt + (size_t)(j0 + jj) * CH + h * HD + d0 + s8);
#pragma unroll
      for (int q = 0; q < 8; ++q) Ws[s8 + q][jj] = (float)v[q];
    }
    if (threadIdx.x < 192) {
      int e = threadIdx.x >> 1, s8 = (threadIdx.x & 1) * 8;
      f16x8 v = *(const f16x8*)(ATt + (size_t)bh * 9216 + (size_t)e * 96 + d0 + s8);
#pragma unroll
      for (int q = 0; q < 8; ++q) Ats[s8 + q][e] = (float)v[q];
    }
    __syncthreads();
#pragma unroll
    for (int kk = 0; kk < 16; ++kk) {
      float a[8], bb[6];
#pragma unroll
      for (int i = 0; i < 8; ++i) a[i] = Ws[kk][ty * 8 + i];
#pragma unroll
      for (int j = 0; j < 6; ++j) bb[j] = Ats[kk][tx * 6 + j];
#pragma unroll
      for (int i = 0; i < 8; ++i)
#pragma unroll
        for (int j = 0; j < 6; ++j)
          acc[i][j] += a[i] * bb[j];
    }
    __syncthreads();
  }

  _Float16* mb = Mt + (size_t)b * CH * CH;
#pragma unroll
  for (int i = 0; i < 8; ++i)
#pragma unroll
    for (int j = 0; j < 6; ++j)
      mb[(size_t)(j0 + ty * 8 + i) * CH + h * HD + tx * 6 + j] = (_Float16)acc[i][j];
}

// ---------------------------------------------------------------------------
extern "C" void kernel_launch(void* const* d_in, const int* in_sizes, int n_in,
                              void* d_out, int out_size, void* d_ws, size_t ws_size,
                              hipStream_t stream) {
  const float* x      = (const float*)d_in[0];
  const float* W_qkv  = (const float*)d_in[1];
  const float* W_proj = (const float*)d_in[2];
  const float* b_proj = (const float*)d_in[3];
  const float* temp   = (const float*)d_in[4];
  float* out = (float*)d_out;
  char* ws = (char*)d_ws;

  _Float16* XT  = (_Float16*)(ws + XT_B);
  _Float16* UT  = (_Float16*)(ws + UT_B);
  _Float16* ATT = (_Float16*)(ws + ATT_B);
  _Float16* MT  = (_Float16*)(ws + MT_B);
  _Float16* PT  = (_Float16*)(ws + PT_B);
  _Float16* GP  = (_Float16*)(ws + GP_B);
  _Float16* XH  = (_Float16*)(ws + XH_B);
  _Float16* WH  = (_Float16*)(ws + WH_B);
  _Float16* WT  = (_Float16*)(ws + WT_B);
  _Float16* WPT = (_Float16*)(ws + WPT_B);
  _Float16* G   = (_Float16*)(ws + G_B);
  float*    INV = (float*)   (ws + INV_B);

  const long CC = (long)CH * CH;           // 589824
  const long SC = (long)SEQ * CH;          // 3145728

  // --- weight converts / transposes, x -> XT ---
  cvt_f16_kernel<<<(CH * NC3 / 4 + 255) / 256, 256, 0, stream>>>(
      W_qkv, WH, CH * NC3 / 4);
  transpose_cvt_kernel<<<dim3(CH / 32, SEQ / 32, NB), 256, 0, stream>>>(
      x, XT, SEQ, CH, SC, SC);
  transpose_cvt_kernel<<<dim3(NC3 / 32, CH / 32, 1), 256, 0, stream>>>(
      W_qkv, WT, CH, NC3, 0, 0);
  transpose_cvt_kernel<<<dim3(CH / 32, CH / 32, 1), 256, 0, stream>>>(
      W_proj, WPT, CH, CH, 0, 0);

  // --- G upper-tri partials: 21 tiles x (8 b x 4 K-chunks) = 672 blocks ---
  gemm_bt_mfma<true, false, true><<<672, 256, 0, stream>>>(
      XT, XT, nullptr, GP, 1024, SEQ, SEQ, CH,
      (long)CH * SEQ, (long)CH * SEQ, CC, NB, 1024, 1024, (long)NB * CC,
      21, 1);

  // --- reduce chunks + mirror to full symmetric G ---
  reduce_mirror_kernel<<<dim3(21, NB), 256, 0, stream>>>(GP, G);

  // --- U fused over t: UT[t][b] = Wt_t . G_b^T  (z = t*8+b) ---
  gemm_bt_mfma<true, false, false><<<576, 256, 0, stream>>>(
      WT, G, nullptr, UT, CH, CH, CH, CH,
      0, CC, CC, NB, CC, 0, (long)NB * CC, 6, 6);

  // --- norms ---
  norm_kernel<<<dim3(16, 6), 128, 0, stream>>>(UT, WT, INV);

  // --- fused S + scale + softmax -> ATt ---
  sattn_kernel<<<64, 256, 0, stream>>>(WT, UT, INV, temp, ATT);

  // --- Mt ---
  mt_kernel<<<dim3(6, 64), 256, 0, stream>>>(WPT, ATT, MT);

  // --- Pt_b = Mt_b . Wv^T ---
  gemm_bt_mfma<true, false, false><<<288, 256, 0, stream>>>(
      MT, WH + 2 * CH, nullptr, PT, CH, CH, NC3, CH,
      CC, 0, CC, NB, 0, 0, 0, 6, 6);

  // --- x -> XH (GP dead now) ---
  cvt_f16_kernel<<<(int)(NB * SC / 4 / 256), 256, 0, stream>>>(
      x, XH, (int)(NB * SC / 4));

  // --- out_b = XH_b . Pt_b^T + bias ---
  gemm_bt_mfma<false, true, false><<<1536, 256, 0, stream>>>(
      XH, PT, b_proj, out, CH, CH, CH, CH,
      SC, CC, SC, NB, 0, 0, 0, 6, 32);
}